// Round 1
// baseline (784.908 us; speedup 1.0000x reference)
//
#include <hip/hip_runtime.h>
#include <hip/hip_bf16.h>
#include <math.h>

#define B_   8
#define N_   4096
#define C_   512
#define H_   8
#define DH_  64
#define TED_ 1280
#define KSEL 409

__device__ inline void f4tov(float4 v, float* o) { o[0]=v.x; o[1]=v.y; o[2]=v.z; o[3]=v.w; }

// ---------------- gating: scores[b,c] ----------------
__global__ __launch_bounds__(256) void k_gating(const float* __restrict__ temb,
    const float* __restrict__ g_w1, const float* __restrict__ g_b1,
    const float* __restrict__ g_w2, const float* __restrict__ g_b2,
    float* __restrict__ scores)
{
  __shared__ float red[256];
  __shared__ float hid[64];
  int b = blockIdx.x, tid = threadIdx.x;
  int j = tid & 63, part = tid >> 6;
  const float* te = temb + b*TED_;
  float s = 0.f;
  for (int t = part*320; t < part*320 + 320; ++t)
    s += te[t] * g_w1[t*64 + j];
  red[tid] = s;
  __syncthreads();
  if (part == 0) {
    float v = red[j] + red[j+64] + red[j+128] + red[j+192] + g_b1[j];
    hid[j] = v / (1.f + __expf(-v));   // silu
  }
  __syncthreads();
  for (int c = tid; c < C_; c += 256) {
    float s2 = g_b2[c];
    #pragma unroll 8
    for (int h = 0; h < 64; ++h) s2 += hid[h] * g_w2[h*C_ + c];
    scores[b*C_ + c] = s2;
  }
}

// ---------------- imp + LN stats (one pass over x) ----------------
__global__ __launch_bounds__(256) void k_imp_stats(const float* __restrict__ x,
    const float* __restrict__ scores, float* __restrict__ imp,
    float* __restrict__ mu, float* __restrict__ rstd)
{
  int tid = threadIdx.x, lane = tid & 63, wid = tid >> 6;
  int token = blockIdx.x*4 + wid;
  int b = token >> 12;
  const float4* xr = (const float4*)(x + (size_t)token*C_);
  const float4* sc = (const float4*)(scores + b*C_);
  float si = 0.f, s1 = 0.f, s2 = 0.f;
  #pragma unroll
  for (int jj = 0; jj < 2; ++jj) {
    float4 xv = xr[lane + 64*jj];
    float4 sv = sc[lane + 64*jj];
    si += xv.x*sv.x + xv.y*sv.y + xv.z*sv.z + xv.w*sv.w;
    s1 += xv.x + xv.y + xv.z + xv.w;
    s2 += xv.x*xv.x + xv.y*xv.y + xv.z*xv.z + xv.w*xv.w;
  }
  #pragma unroll
  for (int off = 32; off >= 1; off >>= 1) {
    si += __shfl_xor(si, off, 64);
    s1 += __shfl_xor(s1, off, 64);
    s2 += __shfl_xor(s2, off, 64);
  }
  if (lane == 0) {
    imp[token] = si;
    float m = s1 * (1.f/C_);
    float var = s2 * (1.f/C_) - m*m;
    mu[token] = m;
    rstd[token] = rsqrtf(var + 1e-5f);
  }
}

// ---------------- deterministic radix-select top-k ----------------
__global__ __launch_bounds__(256) void k_topk(const float* __restrict__ imp,
                                              int* __restrict__ idxout)
{
  __shared__ unsigned skey[4096];
  __shared__ int hist[256];
  __shared__ unsigned s_prefix;
  __shared__ int s_kneed;
  __shared__ int sc_sel[256], sc_tie[256];
  int b = blockIdx.x, tid = threadIdx.x;
  for (int i = tid; i < 4096; i += 256) {
    unsigned u = __float_as_uint(imp[b*N_ + i]);
    skey[i] = (u & 0x80000000u) ? ~u : (u | 0x80000000u);  // monotone key
  }
  if (tid == 0) { s_prefix = 0; s_kneed = KSEL; }
  __syncthreads();
  for (int shift = 24; shift >= 0; shift -= 8) {
    hist[tid] = 0;
    __syncthreads();
    unsigned pref = s_prefix;
    for (int i = tid; i < 4096; i += 256) {
      unsigned key = skey[i];
      bool match;
      if (shift == 24) match = true;
      else match = ((key >> (shift + 8)) == pref);
      if (match) atomicAdd(&hist[(key >> shift) & 255], 1);
    }
    __syncthreads();
    if (tid == 0) {
      int need = s_kneed; int d = 255;
      for (; d > 0; --d) { int hh = hist[d]; if (need <= hh) break; need -= hh; }
      s_prefix = (s_prefix << 8) | (unsigned)d;
      s_kneed = need;
    }
    __syncthreads();
  }
  unsigned T = s_prefix;      // key of the 409th largest
  int tie_take = s_kneed;     // how many ==T to take (lowest indices)
  int lc_sel = 0, lc_tie = 0;
  int i0 = tid * 16;
  for (int e2 = 0; e2 < 16; ++e2) {
    unsigned key = skey[i0 + e2];
    lc_sel += (key > T);
    lc_tie += (key == T);
  }
  sc_sel[tid] = lc_sel; sc_tie[tid] = lc_tie;
  __syncthreads();
  for (int off = 1; off < 256; off <<= 1) {   // inclusive scan
    int a = 0, c2 = 0;
    if (tid >= off) { a = sc_sel[tid - off]; c2 = sc_tie[tid - off]; }
    __syncthreads();
    sc_sel[tid] += a; sc_tie[tid] += c2;
    __syncthreads();
  }
  int total_gt = sc_sel[255];
  int ps = sc_sel[tid] - lc_sel, pt = sc_tie[tid] - lc_tie;
  for (int e2 = 0; e2 < 16; ++e2) {
    int i = i0 + e2;
    unsigned key = skey[i];
    if (key > T) { idxout[b*KSEL + ps] = i; ++ps; }
    else if (key == T) { if (pt < tie_take) idxout[b*KSEL + total_gt + pt] = i; ++pt; }
  }
}

// ---------------- QKV projection with row gather ----------------
__global__ __launch_bounds__(256) void k_qkv(const float* __restrict__ x,
    const int* __restrict__ idx, const float* __restrict__ wq,
    const float* __restrict__ wk, const float* __restrict__ wv,
    float* __restrict__ qb, float* __restrict__ kb, float* __restrict__ vb)
{
  __shared__ float As[16][68];
  __shared__ float Bs[16][68];
  __shared__ int stoken[64];
  int tid = threadIdx.x;
  int mt = blockIdx.x, nt = blockIdx.y, b = blockIdx.z;
  int w = nt >> 3;
  int colw0 = (nt & 7) * 64;
  const float* Bsrc = (w == 0) ? wq : (w == 1) ? wk : wv;
  float* outw = (w == 0) ? qb : (w == 1) ? kb : vb;
  int m0 = mt * 64;
  if (tid < 64) {
    int r = m0 + tid;
    stoken[tid] = idx[b*KSEL + (r < KSEL ? r : 0)];
  }
  __syncthreads();
  int tr = tid >> 4, tc = tid & 15;
  int m_l = tid >> 2, kq = tid & 3;
  float acc[4][4] = {};
  for (int k0 = 0; k0 < C_; k0 += 16) {
    float4 av = *(const float4*)&x[((size_t)b*N_ + stoken[m_l])*C_ + k0 + kq*4];
    float4 bv = *(const float4*)&Bsrc[(size_t)(k0 + tr)*C_ + colw0 + tc*4];
    As[kq*4+0][m_l] = av.x; As[kq*4+1][m_l] = av.y;
    As[kq*4+2][m_l] = av.z; As[kq*4+3][m_l] = av.w;
    *(float4*)&Bs[tr][tc*4] = bv;
    __syncthreads();
    #pragma unroll
    for (int kk = 0; kk < 16; ++kk) {
      float ar[4], br[4];
      f4tov(*(const float4*)&As[kk][tr*4], ar);
      f4tov(*(const float4*)&Bs[kk][tc*4], br);
      #pragma unroll
      for (int i = 0; i < 4; ++i)
        #pragma unroll
        for (int j = 0; j < 4; ++j) acc[i][j] += ar[i]*br[j];
    }
    __syncthreads();
  }
  size_t obase = (((size_t)b*H_ + (nt & 7)) * KSEL) * DH_;
  #pragma unroll
  for (int i = 0; i < 4; ++i) {
    int r = m0 + tr*4 + i;
    if (r < KSEL) {
      float4 o = make_float4(acc[i][0], acc[i][1], acc[i][2], acc[i][3]);
      *(float4*)&outw[obase + (size_t)r*DH_ + tc*4] = o;
    }
  }
}

// ---------------- flash attention over routed tokens ----------------
__global__ __launch_bounds__(256) void k_attn(const float* __restrict__ qb,
    const float* __restrict__ kb, const float* __restrict__ vb,
    float* __restrict__ sa)
{
  __shared__ float Qs[64][68];
  __shared__ float KPs[64][68];   // K tile, reused for P
  __shared__ float Vs[64][68];
  int tid = threadIdx.x;
  int qt = blockIdx.x, h = blockIdx.y, b = blockIdx.z;
  int tr = tid >> 4, tc = tid & 15;
  size_t base = (((size_t)b*H_) + h) * KSEL * DH_;
  int r0 = qt * 64;
  #pragma unroll
  for (int jj = 0; jj < 4; ++jj) {
    int f = jj*256 + tid;
    int rr = f >> 4, dd = (f & 15) * 4;
    float4 v = make_float4(0.f, 0.f, 0.f, 0.f);
    int r = r0 + rr;
    if (r < KSEL) v = *(const float4*)&qb[base + (size_t)r*DH_ + dd];
    *(float4*)&Qs[rr][dd] = v;
  }
  float m_run[4], l_run[4], acc[4][4] = {};
  #pragma unroll
  for (int i = 0; i < 4; ++i) { m_run[i] = -1e30f; l_run[i] = 0.f; }
  for (int t = 0; t < 7; ++t) {
    int kt0 = t * 64;
    __syncthreads();
    #pragma unroll
    for (int jj = 0; jj < 4; ++jj) {
      int f = jj*256 + tid;
      int rr = f >> 4, dd = (f & 15) * 4;
      int r = kt0 + rr;
      float4 kv = make_float4(0.f,0.f,0.f,0.f), vv = make_float4(0.f,0.f,0.f,0.f);
      if (r < KSEL) {
        kv = *(const float4*)&kb[base + (size_t)r*DH_ + dd];
        vv = *(const float4*)&vb[base + (size_t)r*DH_ + dd];
      }
      *(float4*)&KPs[rr][dd] = kv;
      *(float4*)&Vs[rr][dd] = vv;
    }
    __syncthreads();
    float s[4][4] = {};
    for (int d4 = 0; d4 < 64; d4 += 4) {
      float qa[4][4], ka[4][4];
      #pragma unroll
      for (int i = 0; i < 4; ++i) f4tov(*(const float4*)&Qs[tr*4+i][d4], qa[i]);
      #pragma unroll
      for (int j = 0; j < 4; ++j) f4tov(*(const float4*)&KPs[tc*4+j][d4], ka[j]);
      #pragma unroll
      for (int i = 0; i < 4; ++i)
        #pragma unroll
        for (int j = 0; j < 4; ++j)
          s[i][j] += qa[i][0]*ka[j][0] + qa[i][1]*ka[j][1]
                   + qa[i][2]*ka[j][2] + qa[i][3]*ka[j][3];
    }
    #pragma unroll
    for (int i = 0; i < 4; ++i)
      #pragma unroll
      for (int j = 0; j < 4; ++j) {
        float v = s[i][j] * 0.125f;                 // DH^-0.5
        if (kt0 + tc*4 + j >= KSEL) v = -1e30f;
        s[i][j] = v;
      }
    #pragma unroll
    for (int i = 0; i < 4; ++i) {
      float tm = fmaxf(fmaxf(s[i][0], s[i][1]), fmaxf(s[i][2], s[i][3]));
      #pragma unroll
      for (int off = 1; off < 16; off <<= 1) tm = fmaxf(tm, __shfl_xor(tm, off, 64));
      float mnew = fmaxf(m_run[i], tm);
      float corr = __expf(m_run[i] - mnew);
      float rs = 0.f;
      #pragma unroll
      for (int j = 0; j < 4; ++j) { float p = __expf(s[i][j] - mnew); s[i][j] = p; rs += p; }
      #pragma unroll
      for (int off = 1; off < 16; off <<= 1) rs += __shfl_xor(rs, off, 64);
      l_run[i] = l_run[i]*corr + rs;
      m_run[i] = mnew;
      #pragma unroll
      for (int j = 0; j < 4; ++j) acc[i][j] *= corr;
    }
    __syncthreads();                 // everyone done reading K tile
    #pragma unroll
    for (int i = 0; i < 4; ++i)
      *(float4*)&KPs[tr*4+i][tc*4] = make_float4(s[i][0], s[i][1], s[i][2], s[i][3]);
    __syncthreads();
    for (int j4 = 0; j4 < 64; j4 += 4) {
      float pa[4][4], va[4][4];
      #pragma unroll
      for (int i = 0; i < 4; ++i) f4tov(*(const float4*)&KPs[tr*4+i][j4], pa[i]);
      #pragma unroll
      for (int j = 0; j < 4; ++j) f4tov(*(const float4*)&Vs[j4+j][tc*4], va[j]);
      #pragma unroll
      for (int i = 0; i < 4; ++i)
        #pragma unroll
        for (int j = 0; j < 4; ++j)
          acc[i][j] += pa[i][0]*va[0][j] + pa[i][1]*va[1][j]
                     + pa[i][2]*va[2][j] + pa[i][3]*va[3][j];
    }
  }
  #pragma unroll
  for (int i = 0; i < 4; ++i) {
    int r = r0 + tr*4 + i;
    if (r < KSEL) {
      float inv = 1.f / l_run[i];
      float4 o = make_float4(acc[i][0]*inv, acc[i][1]*inv, acc[i][2]*inv, acc[i][3]*inv);
      *(float4*)&sa[((size_t)b*KSEL + r)*C_ + h*DH_ + tc*4] = o;
    }
  }
}

// ---------------- e = LN(x) @ ea_k^T, scaled ----------------
__global__ __launch_bounds__(256) void k_e_gemm(const float* __restrict__ x,
    const float* __restrict__ mu, const float* __restrict__ rstd,
    const float* __restrict__ ln_g, const float* __restrict__ ln_b,
    const float* __restrict__ ea_k, float* __restrict__ e)
{
  __shared__ float As[16][68];
  __shared__ float Bs[16][68];
  int tid = threadIdx.x;
  int m0 = blockIdx.x * 64, col0 = blockIdx.y * 64;
  int tr = tid >> 4, tc = tid & 15;
  int m_l = tid >> 2, kq = tid & 3;
  int row = m0 + m_l;
  float muv = mu[row], rs = rstd[row];
  float acc[4][4] = {};
  for (int k0 = 0; k0 < C_; k0 += 16) {
    float4 xv = *(const float4*)&x[(size_t)row*C_ + k0 + kq*4];
    float4 g4 = *(const float4*)&ln_g[k0 + kq*4];
    float4 b4 = *(const float4*)&ln_b[k0 + kq*4];
    As[kq*4+0][m_l] = (xv.x - muv)*rs*g4.x + b4.x;
    As[kq*4+1][m_l] = (xv.y - muv)*rs*g4.y + b4.y;
    As[kq*4+2][m_l] = (xv.z - muv)*rs*g4.z + b4.z;
    As[kq*4+3][m_l] = (xv.w - muv)*rs*g4.w + b4.w;
    float4 bv = *(const float4*)&ea_k[(size_t)(col0 + m_l)*C_ + k0 + kq*4];
    Bs[kq*4+0][m_l] = bv.x; Bs[kq*4+1][m_l] = bv.y;
    Bs[kq*4+2][m_l] = bv.z; Bs[kq*4+3][m_l] = bv.w;
    __syncthreads();
    #pragma unroll
    for (int kk = 0; kk < 16; ++kk) {
      float ar[4], br[4];
      f4tov(*(const float4*)&As[kk][tr*4], ar);
      f4tov(*(const float4*)&Bs[kk][tc*4], br);
      #pragma unroll
      for (int i = 0; i < 4; ++i)
        #pragma unroll
        for (int j = 0; j < 4; ++j) acc[i][j] += ar[i]*br[j];
    }
    __syncthreads();
  }
  #pragma unroll
  for (int i = 0; i < 4; ++i) {
    size_t o = (size_t)(m0 + tr*4 + i)*C_ + col0 + tc*4;
    *(float4*)&e[o] = make_float4(acc[i][0]*0.125f, acc[i][1]*0.125f,
                                  acc[i][2]*0.125f, acc[i][3]*0.125f);
  }
}

// ---------------- column sums of exp(s) over tokens ----------------
__global__ __launch_bounds__(256) void k_colsum_part(const float* __restrict__ e,
                                                     float* __restrict__ psum)
{
  int ncb = blockIdx.x, ic = blockIdx.y, b = blockIdx.z;
  int tid = threadIdx.x, il = tid & 63, nsub = tid >> 6;
  int i = ic*64 + il;
  float s = 0.f;
  for (int n = ncb*512 + nsub; n < ncb*512 + 512; n += 4)
    s += __expf(e[((size_t)b*N_ + n)*C_ + i]);
  __shared__ float red[256];
  red[tid] = s; __syncthreads();
  if (nsub == 0)
    psum[((size_t)b*C_ + i)*8 + ncb] = red[il] + red[il+64] + red[il+128] + red[il+192];
}

__global__ __launch_bounds__(256) void k_colsum_comb(const float* __restrict__ psum,
                                                     float* __restrict__ colsum)
{
  int g = blockIdx.x*256 + threadIdx.x;   // 0..4095 = (b, i)
  float s = 0.f;
  #pragma unroll
  for (int c = 0; c < 8; ++c) s += psum[(size_t)g*8 + c];
  colsum[g] = s;
}

// ---------------- softmax value + head-normalize (in place) ----------------
__global__ __launch_bounds__(256) void k_anorm(float* __restrict__ e,
                                               const float* __restrict__ colsum)
{
  int tid = threadIdx.x, lane = tid & 63, wid = tid >> 6;
  int token = blockIdx.x*4 + wid;
  int b = token >> 12;
  size_t base = (size_t)token*C_ + lane*8;
  float4 v0 = *(const float4*)&e[base];
  float4 v1 = *(const float4*)&e[base + 4];
  const float* cs = colsum + b*C_ + lane*8;
  float4 c0 = *(const float4*)&cs[0];
  float4 c1 = *(const float4*)&cs[4];
  float a[8];
  a[0] = __expf(v0.x)/c0.x; a[1] = __expf(v0.y)/c0.y;
  a[2] = __expf(v0.z)/c0.z; a[3] = __expf(v0.w)/c0.w;
  a[4] = __expf(v1.x)/c1.x; a[5] = __expf(v1.y)/c1.y;
  a[6] = __expf(v1.z)/c1.z; a[7] = __expf(v1.w)/c1.w;
  float hs = a[0]+a[1]+a[2]+a[3]+a[4]+a[5]+a[6]+a[7];
  hs += __shfl_xor(hs, 1, 64);
  hs += __shfl_xor(hs, 2, 64);
  hs += __shfl_xor(hs, 4, 64);   // 8-lane group == one head (64 dims)
  hs += 1e-6f;
  float r = 1.f / hs;
  *(float4*)&e[base]     = make_float4(a[0]*r, a[1]*r, a[2]*r, a[3]*r);
  *(float4*)&e[base + 4] = make_float4(a[4]*r, a[5]*r, a[6]*r, a[7]*r);
}

// ---------------- ea = a @ ea_v^T -> d_out ----------------
__global__ __launch_bounds__(256) void k_ea_gemm(const float* __restrict__ a,
    const float* __restrict__ ea_v, float* __restrict__ out)
{
  __shared__ float As[16][68];
  __shared__ float Bs[16][68];
  int tid = threadIdx.x;
  int m0 = blockIdx.x * 64, col0 = blockIdx.y * 64;
  int tr = tid >> 4, tc = tid & 15;
  int m_l = tid >> 2, kq = tid & 3;
  int row = m0 + m_l;
  float acc[4][4] = {};
  for (int k0 = 0; k0 < C_; k0 += 16) {
    float4 av = *(const float4*)&a[(size_t)row*C_ + k0 + kq*4];
    As[kq*4+0][m_l] = av.x; As[kq*4+1][m_l] = av.y;
    As[kq*4+2][m_l] = av.z; As[kq*4+3][m_l] = av.w;
    float4 bv = *(const float4*)&ea_v[(size_t)(col0 + m_l)*C_ + k0 + kq*4];
    Bs[kq*4+0][m_l] = bv.x; Bs[kq*4+1][m_l] = bv.y;
    Bs[kq*4+2][m_l] = bv.z; Bs[kq*4+3][m_l] = bv.w;
    __syncthreads();
    #pragma unroll
    for (int kk = 0; kk < 16; ++kk) {
      float ar[4], br[4];
      f4tov(*(const float4*)&As[kk][tr*4], ar);
      f4tov(*(const float4*)&Bs[kk][tc*4], br);
      #pragma unroll
      for (int i = 0; i < 4; ++i)
        #pragma unroll
        for (int j = 0; j < 4; ++j) acc[i][j] += ar[i]*br[j];
    }
    __syncthreads();
  }
  #pragma unroll
  for (int i = 0; i < 4; ++i) {
    size_t o = (size_t)(m0 + tr*4 + i)*C_ + col0 + tc*4;
    *(float4*)&out[o] = make_float4(acc[i][0], acc[i][1], acc[i][2], acc[i][3]);
  }
}

// ---------------- sa@wo + bo, scatter-add alpha*() into d_out ----------------
__global__ __launch_bounds__(256) void k_sa_gemm(const float* __restrict__ sa,
    const float* __restrict__ wo, const float* __restrict__ bo,
    const int* __restrict__ idx, const float* __restrict__ alphap,
    float* __restrict__ out)
{
  __shared__ float As[16][68];
  __shared__ float Bs[16][68];
  int tid = threadIdx.x;
  int mt = blockIdx.x, nt = blockIdx.y, b = blockIdx.z;
  int m0 = mt*64, col0 = nt*64;
  int tr = tid >> 4, tc = tid & 15;
  int m_l = tid >> 2, kq = tid & 3;
  int arow = m0 + m_l; if (arow >= KSEL) arow = 0;
  float acc[4][4] = {};
  for (int k0 = 0; k0 < C_; k0 += 16) {
    float4 av = *(const float4*)&sa[((size_t)b*KSEL + arow)*C_ + k0 + kq*4];
    float4 bv = *(const float4*)&wo[(size_t)(k0 + tr)*C_ + col0 + tc*4];
    As[kq*4+0][m_l] = av.x; As[kq*4+1][m_l] = av.y;
    As[kq*4+2][m_l] = av.z; As[kq*4+3][m_l] = av.w;
    *(float4*)&Bs[tr][tc*4] = bv;
    __syncthreads();
    #pragma unroll
    for (int kk = 0; kk < 16; ++kk) {
      float ar[4], br[4];
      f4tov(*(const float4*)&As[kk][tr*4], ar);
      f4tov(*(const float4*)&Bs[kk][tc*4], br);
      #pragma unroll
      for (int i = 0; i < 4; ++i)
        #pragma unroll
        for (int j = 0; j < 4; ++j) acc[i][j] += ar[i]*br[j];
    }
    __syncthreads();
  }
  float alpha = alphap[0];
  float4 bo4 = *(const float4*)&bo[col0 + tc*4];
  #pragma unroll
  for (int i = 0; i < 4; ++i) {
    int r = m0 + tr*4 + i;
    if (r < KSEL) {
      int token = idx[b*KSEL + r];
      size_t o = ((size_t)b*N_ + token)*C_ + col0 + tc*4;
      float4 cur = *(float4*)&out[o];
      cur.x += alpha*(acc[i][0] + bo4.x);
      cur.y += alpha*(acc[i][1] + bo4.y);
      cur.z += alpha*(acc[i][2] + bo4.z);
      cur.w += alpha*(acc[i][3] + bo4.w);
      *(float4*)&out[o] = cur;
    }
  }
}

extern "C" void kernel_launch(void* const* d_in, const int* in_sizes, int n_in,
                              void* d_out, int out_size, void* d_ws, size_t ws_size,
                              hipStream_t stream)
{
  const float* x     = (const float*)d_in[0];
  const float* temb  = (const float*)d_in[1];
  const float* g_w1  = (const float*)d_in[2];
  const float* g_b1  = (const float*)d_in[3];
  const float* g_w2  = (const float*)d_in[4];
  const float* g_b2  = (const float*)d_in[5];
  const float* wq    = (const float*)d_in[6];
  const float* wk    = (const float*)d_in[7];
  const float* wv    = (const float*)d_in[8];
  const float* wo    = (const float*)d_in[9];
  const float* bo    = (const float*)d_in[10];
  const float* ln_g  = (const float*)d_in[11];
  const float* ln_b  = (const float*)d_in[12];
  const float* ea_k  = (const float*)d_in[13];
  const float* ea_v  = (const float*)d_in[14];
  const float* alpha = (const float*)d_in[15];
  float* out = (float*)d_out;
  float* ws = (float*)d_ws;

  // workspace layout (floats); total ~23.62M floats ~ 94.5 MB
  float* scores = ws;                      // 4096
  float* imp    = ws + 4096;               // 32768
  float* mu     = ws + 36864;              // 32768
  float* rstd   = ws + 69632;              // 32768
  int*   idx    = (int*)(ws + 102400);     // 4096 slots (409*8 used)
  float* qb     = ws + 106496;             // 8*8*409*64 = 1675264
  float* kb     = qb + 1675264;
  float* vb     = kb + 1675264;
  float* sab    = vb + 1675264;            // 8*409*512
  float* ebuf   = sab + 1675264;           // 8*4096*512 = 16777216
  float* colsum = ebuf + 16777216;         // 4096
  float* psum   = colsum + 4096;           // 32768

  k_gating     <<<dim3(B_),        dim3(256), 0, stream>>>(temb, g_w1, g_b1, g_w2, g_b2, scores);
  k_imp_stats  <<<dim3(B_*N_/4),   dim3(256), 0, stream>>>(x, scores, imp, mu, rstd);
  k_topk       <<<dim3(B_),        dim3(256), 0, stream>>>(imp, idx);
  k_qkv        <<<dim3(7, 24, B_), dim3(256), 0, stream>>>(x, idx, wq, wk, wv, qb, kb, vb);
  k_attn       <<<dim3(7, H_, B_), dim3(256), 0, stream>>>(qb, kb, vb, sab);
  k_e_gemm     <<<dim3(512, 8),    dim3(256), 0, stream>>>(x, mu, rstd, ln_g, ln_b, ea_k, ebuf);
  k_colsum_part<<<dim3(8, 8, B_),  dim3(256), 0, stream>>>(ebuf, psum);
  k_colsum_comb<<<dim3(16),        dim3(256), 0, stream>>>(psum, colsum);
  k_anorm      <<<dim3(B_*N_/4),   dim3(256), 0, stream>>>(ebuf, colsum);
  k_ea_gemm    <<<dim3(512, 8),    dim3(256), 0, stream>>>(ebuf, ea_v, out);
  k_sa_gemm    <<<dim3(7, 8, B_),  dim3(256), 0, stream>>>(sab, wo, bo, idx, alpha, out);
}

// Round 2
// 395.696 us; speedup vs baseline: 1.9836x; 1.9836x over previous
//
#include <hip/hip_runtime.h>
#include <hip/hip_bf16.h>
#include <math.h>

#define B_   8
#define N_   4096
#define C_   512
#define H_   8
#define DH_  64
#define TED_ 1280
#define KSEL 409

typedef __attribute__((ext_vector_type(8))) short bf16x8;
typedef __attribute__((ext_vector_type(4))) float f32x4;

__device__ inline void f4tov(float4 v, float* o) { o[0]=v.x; o[1]=v.y; o[2]=v.z; o[3]=v.w; }

// round-to-nearest-even float -> bf16 bits (finite values)
__device__ __forceinline__ unsigned short f2bf(float f) {
  unsigned u = __float_as_uint(f);
  unsigned r = u + 0x7fffu + ((u >> 16) & 1u);
  return (unsigned short)(r >> 16);
}
__device__ __forceinline__ float bf2f(unsigned short s) {
  return __uint_as_float(((unsigned)s) << 16);
}

__device__ __forceinline__ void gload16(const void* g, void* l) {
  __builtin_amdgcn_global_load_lds(
      (const __attribute__((address_space(1))) void*)g,
      (__attribute__((address_space(3))) void*)l,
      16, 0, 0);
}

// ---------------- gating: scores[b,c] ----------------
__global__ __launch_bounds__(256) void k_gating(const float* __restrict__ temb,
    const float* __restrict__ g_w1, const float* __restrict__ g_b1,
    const float* __restrict__ g_w2, const float* __restrict__ g_b2,
    float* __restrict__ scores)
{
  __shared__ float red[256];
  __shared__ float hid[64];
  int b = blockIdx.x, tid = threadIdx.x;
  int j = tid & 63, part = tid >> 6;
  const float* te = temb + b*TED_;
  float s = 0.f;
  for (int t = part*320; t < part*320 + 320; ++t)
    s += te[t] * g_w1[t*64 + j];
  red[tid] = s;
  __syncthreads();
  if (part == 0) {
    float v = red[j] + red[j+64] + red[j+128] + red[j+192] + g_b1[j];
    hid[j] = v / (1.f + __expf(-v));   // silu
  }
  __syncthreads();
  for (int c = tid; c < C_; c += 256) {
    float s2 = g_b2[c];
    #pragma unroll 8
    for (int h = 0; h < 64; ++h) s2 += hid[h] * g_w2[h*C_ + c];
    scores[b*C_ + c] = s2;
  }
}

// ---------------- imp + LN stats (one pass over x) ----------------
__global__ __launch_bounds__(256) void k_imp_stats(const float* __restrict__ x,
    const float* __restrict__ scores, float* __restrict__ imp,
    float* __restrict__ mu, float* __restrict__ rstd)
{
  int tid = threadIdx.x, lane = tid & 63, wid = tid >> 6;
  int token = blockIdx.x*4 + wid;
  int b = token >> 12;
  const float4* xr = (const float4*)(x + (size_t)token*C_);
  const float4* sc = (const float4*)(scores + b*C_);
  float si = 0.f, s1 = 0.f, s2 = 0.f;
  #pragma unroll
  for (int jj = 0; jj < 2; ++jj) {
    float4 xv = xr[lane + 64*jj];
    float4 sv = sc[lane + 64*jj];
    si += xv.x*sv.x + xv.y*sv.y + xv.z*sv.z + xv.w*sv.w;
    s1 += xv.x + xv.y + xv.z + xv.w;
    s2 += xv.x*xv.x + xv.y*xv.y + xv.z*xv.z + xv.w*xv.w;
  }
  #pragma unroll
  for (int off = 32; off >= 1; off >>= 1) {
    si += __shfl_xor(si, off, 64);
    s1 += __shfl_xor(s1, off, 64);
    s2 += __shfl_xor(s2, off, 64);
  }
  if (lane == 0) {
    imp[token] = si;
    float m = s1 * (1.f/C_);
    float var = s2 * (1.f/C_) - m*m;
    mu[token] = m;
    rstd[token] = rsqrtf(var + 1e-5f);
  }
}

// ---------------- deterministic radix-select top-k ----------------
__global__ __launch_bounds__(256) void k_topk(const float* __restrict__ imp,
                                              int* __restrict__ idxout)
{
  __shared__ unsigned skey[4096];
  __shared__ int hist[256];
  __shared__ unsigned s_prefix;
  __shared__ int s_kneed;
  __shared__ int sc_sel[256], sc_tie[256];
  int b = blockIdx.x, tid = threadIdx.x;
  for (int i = tid; i < 4096; i += 256) {
    unsigned u = __float_as_uint(imp[b*N_ + i]);
    skey[i] = (u & 0x80000000u) ? ~u : (u | 0x80000000u);  // monotone key
  }
  if (tid == 0) { s_prefix = 0; s_kneed = KSEL; }
  __syncthreads();
  for (int shift = 24; shift >= 0; shift -= 8) {
    hist[tid] = 0;
    __syncthreads();
    unsigned pref = s_prefix;
    for (int i = tid; i < 4096; i += 256) {
      unsigned key = skey[i];
      bool match;
      if (shift == 24) match = true;
      else match = ((key >> (shift + 8)) == pref);
      if (match) atomicAdd(&hist[(key >> shift) & 255], 1);
    }
    __syncthreads();
    if (tid == 0) {
      int need = s_kneed; int d = 255;
      for (; d > 0; --d) { int hh = hist[d]; if (need <= hh) break; need -= hh; }
      s_prefix = (s_prefix << 8) | (unsigned)d;
      s_kneed = need;
    }
    __syncthreads();
  }
  unsigned T = s_prefix;      // key of the 409th largest
  int tie_take = s_kneed;     // how many ==T to take (lowest indices)
  int lc_sel = 0, lc_tie = 0;
  int i0 = tid * 16;
  for (int e2 = 0; e2 < 16; ++e2) {
    unsigned key = skey[i0 + e2];
    lc_sel += (key > T);
    lc_tie += (key == T);
  }
  sc_sel[tid] = lc_sel; sc_tie[tid] = lc_tie;
  __syncthreads();
  for (int off = 1; off < 256; off <<= 1) {   // inclusive scan
    int a = 0, c2 = 0;
    if (tid >= off) { a = sc_sel[tid - off]; c2 = sc_tie[tid - off]; }
    __syncthreads();
    sc_sel[tid] += a; sc_tie[tid] += c2;
    __syncthreads();
  }
  int total_gt = sc_sel[255];
  int ps = sc_sel[tid] - lc_sel, pt = sc_tie[tid] - lc_tie;
  for (int e2 = 0; e2 < 16; ++e2) {
    int i = i0 + e2;
    unsigned key = skey[i];
    if (key > T) { idxout[b*KSEL + ps] = i; ++ps; }
    else if (key == T) { if (pt < tie_take) idxout[b*KSEL + total_gt + pt] = i; ++pt; }
  }
}

// ---------------- LN(x) -> bf16 (one token per wave) ----------------
__global__ __launch_bounds__(256) void k_prep(const float* __restrict__ x,
    const float* __restrict__ mu, const float* __restrict__ rstd,
    const float* __restrict__ ln_g, const float* __restrict__ ln_b,
    unsigned short* __restrict__ xn)
{
  int tid = threadIdx.x, lane = tid & 63, wid = tid >> 6;
  int token = blockIdx.x*4 + wid;
  size_t base = (size_t)token*C_ + lane*8;
  float m = mu[token], rs = rstd[token];
  float4 v0 = *(const float4*)&x[base];
  float4 v1 = *(const float4*)&x[base + 4];
  float4 g0 = *(const float4*)&ln_g[lane*8];
  float4 g1 = *(const float4*)&ln_g[lane*8 + 4];
  float4 b0 = *(const float4*)&ln_b[lane*8];
  float4 b1 = *(const float4*)&ln_b[lane*8 + 4];
  unsigned r0 = (unsigned)f2bf((v0.x-m)*rs*g0.x + b0.x) | ((unsigned)f2bf((v0.y-m)*rs*g0.y + b0.y) << 16);
  unsigned r1 = (unsigned)f2bf((v0.z-m)*rs*g0.z + b0.z) | ((unsigned)f2bf((v0.w-m)*rs*g0.w + b0.w) << 16);
  unsigned r2 = (unsigned)f2bf((v1.x-m)*rs*g1.x + b1.x) | ((unsigned)f2bf((v1.y-m)*rs*g1.y + b1.y) << 16);
  unsigned r3 = (unsigned)f2bf((v1.z-m)*rs*g1.z + b1.z) | ((unsigned)f2bf((v1.w-m)*rs*g1.w + b1.w) << 16);
  uint4 o; o.x = r0; o.y = r1; o.z = r2; o.w = r3;
  *(uint4*)&xn[base] = o;
}

// ---------------- fp32 -> bf16 weight convert ----------------
__global__ __launch_bounds__(256) void k_cvt(const float* __restrict__ src,
                                             unsigned short* __restrict__ dst)
{
  int i = (blockIdx.x*256 + threadIdx.x)*4;
  float4 v = *(const float4*)&src[i];
  unsigned lo = (unsigned)f2bf(v.x) | ((unsigned)f2bf(v.y) << 16);
  unsigned hi = (unsigned)f2bf(v.z) | ((unsigned)f2bf(v.w) << 16);
  uint2 o; o.x = lo; o.y = hi;
  *(uint2*)&dst[i] = o;
}

// ---------------- bf16 MFMA GEMM: C[M][512] = A[M][512] @ B[512][512]^T ----
// EPI 0: scale + bf16 store   EPI 1: f32 store
template<int EPI>
__global__ __launch_bounds__(256) void k_mfma_gemm(
    const unsigned short* __restrict__ A,
    const unsigned short* __restrict__ Bm,
    void* __restrict__ Co, float scale)
{
  __shared__ unsigned short As[128*64];
  __shared__ unsigned short Bs[128*64];
  int tid = threadIdx.x;
  int m0 = blockIdx.x * 128, n0 = blockIdx.y * 128;
  int lane = tid & 63, wid = tid >> 6;
  int wr = wid >> 1, wc = wid & 1;
  int srow = tid >> 3;   // staging row within 32-row group
  int spos = tid & 7;    // staging 16B-chunk position

  f32x4 zero = {0.f, 0.f, 0.f, 0.f};
  f32x4 acc[4][4];
  #pragma unroll
  for (int m = 0; m < 4; ++m)
    #pragma unroll
    for (int n = 0; n < 4; ++n) acc[m][n] = zero;

  int l15 = lane & 15, lh = lane >> 4;

  for (int k0 = 0; k0 < C_; k0 += 64) {
    // stage A,B tiles: linear LDS dest, inverse-swizzled global source
    #pragma unroll
    for (int s = 0; s < 4; ++s) {
      int row = s*32 + srow;
      int chunk = spos ^ (row & 7);
      gload16(&A[(size_t)(m0 + row)*C_ + k0 + chunk*8], &As[row*64 + spos*8]);
      gload16(&Bm[(size_t)(n0 + row)*C_ + k0 + chunk*8], &Bs[row*64 + spos*8]);
    }
    __syncthreads();   // vmcnt(0) drain + barrier
    #pragma unroll
    for (int kk = 0; kk < 2; ++kk) {
      bf16x8 af[4], bfr[4];
      #pragma unroll
      for (int m = 0; m < 4; ++m) {
        int row = wr*64 + m*16 + l15;
        int chunk = (kk*4 + lh) ^ (row & 7);
        af[m] = *(const bf16x8*)&As[row*64 + chunk*8];
      }
      #pragma unroll
      for (int n = 0; n < 4; ++n) {
        int row = wc*64 + n*16 + l15;
        int chunk = (kk*4 + lh) ^ (row & 7);
        bfr[n] = *(const bf16x8*)&Bs[row*64 + chunk*8];
      }
      #pragma unroll
      for (int m = 0; m < 4; ++m)
        #pragma unroll
        for (int n = 0; n < 4; ++n)
          acc[m][n] = __builtin_amdgcn_mfma_f32_16x16x32_bf16(af[m], bfr[n], acc[m][n], 0, 0, 0);
    }
    __syncthreads();   // all reads done before next stage overwrites
  }

  #pragma unroll
  for (int m = 0; m < 4; ++m) {
    int row = m0 + wr*64 + m*16 + lh*4;
    #pragma unroll
    for (int n = 0; n < 4; ++n) {
      int col = n0 + wc*64 + n*16 + l15;
      #pragma unroll
      for (int r = 0; r < 4; ++r) {
        float v = acc[m][n][r] * scale;
        if (EPI == 0) ((unsigned short*)Co)[(size_t)(row + r)*C_ + col] = f2bf(v);
        else          ((float*)Co)[(size_t)(row + r)*C_ + col] = v;
      }
    }
  }
}

// ---------------- QKV projection with row gather (fp32) ----------------
__global__ __launch_bounds__(256) void k_qkv(const float* __restrict__ x,
    const int* __restrict__ idx, const float* __restrict__ wq,
    const float* __restrict__ wk, const float* __restrict__ wv,
    float* __restrict__ qb, float* __restrict__ kb, float* __restrict__ vb)
{
  __shared__ float As[16][68];
  __shared__ float Bs[16][68];
  __shared__ int stoken[64];
  int tid = threadIdx.x;
  int mt = blockIdx.x, nt = blockIdx.y, b = blockIdx.z;
  int w = nt >> 3;
  int colw0 = (nt & 7) * 64;
  const float* Bsrc = (w == 0) ? wq : (w == 1) ? wk : wv;
  float* outw = (w == 0) ? qb : (w == 1) ? kb : vb;
  int m0 = mt * 64;
  if (tid < 64) {
    int r = m0 + tid;
    stoken[tid] = idx[b*KSEL + (r < KSEL ? r : 0)];
  }
  __syncthreads();
  int tr = tid >> 4, tc = tid & 15;
  int m_l = tid >> 2, kq = tid & 3;
  float acc[4][4] = {};
  for (int k0 = 0; k0 < C_; k0 += 16) {
    float4 av = *(const float4*)&x[((size_t)b*N_ + stoken[m_l])*C_ + k0 + kq*4];
    float4 bv = *(const float4*)&Bsrc[(size_t)(k0 + tr)*C_ + colw0 + tc*4];
    As[kq*4+0][m_l] = av.x; As[kq*4+1][m_l] = av.y;
    As[kq*4+2][m_l] = av.z; As[kq*4+3][m_l] = av.w;
    *(float4*)&Bs[tr][tc*4] = bv;
    __syncthreads();
    #pragma unroll
    for (int kk = 0; kk < 16; ++kk) {
      float ar[4], br[4];
      f4tov(*(const float4*)&As[kk][tr*4], ar);
      f4tov(*(const float4*)&Bs[kk][tc*4], br);
      #pragma unroll
      for (int i = 0; i < 4; ++i)
        #pragma unroll
        for (int j = 0; j < 4; ++j) acc[i][j] += ar[i]*br[j];
    }
    __syncthreads();
  }
  size_t obase = (((size_t)b*H_ + (nt & 7)) * KSEL) * DH_;
  #pragma unroll
  for (int i = 0; i < 4; ++i) {
    int r = m0 + tr*4 + i;
    if (r < KSEL) {
      float4 o = make_float4(acc[i][0], acc[i][1], acc[i][2], acc[i][3]);
      *(float4*)&outw[obase + (size_t)r*DH_ + tc*4] = o;
    }
  }
}

// ---------------- flash attention over routed tokens (fp32) ----------------
__global__ __launch_bounds__(256) void k_attn(const float* __restrict__ qb,
    const float* __restrict__ kb, const float* __restrict__ vb,
    float* __restrict__ sa)
{
  __shared__ float Qs[64][68];
  __shared__ float KPs[64][68];   // K tile, reused for P
  __shared__ float Vs[64][68];
  int tid = threadIdx.x;
  int qt = blockIdx.x, h = blockIdx.y, b = blockIdx.z;
  int tr = tid >> 4, tc = tid & 15;
  size_t base = (((size_t)b*H_) + h) * KSEL * DH_;
  int r0 = qt * 64;
  #pragma unroll
  for (int jj = 0; jj < 4; ++jj) {
    int f = jj*256 + tid;
    int rr = f >> 4, dd = (f & 15) * 4;
    float4 v = make_float4(0.f, 0.f, 0.f, 0.f);
    int r = r0 + rr;
    if (r < KSEL) v = *(const float4*)&qb[base + (size_t)r*DH_ + dd];
    *(float4*)&Qs[rr][dd] = v;
  }
  float m_run[4], l_run[4], acc[4][4] = {};
  #pragma unroll
  for (int i = 0; i < 4; ++i) { m_run[i] = -1e30f; l_run[i] = 0.f; }
  for (int t = 0; t < 7; ++t) {
    int kt0 = t * 64;
    __syncthreads();
    #pragma unroll
    for (int jj = 0; jj < 4; ++jj) {
      int f = jj*256 + tid;
      int rr = f >> 4, dd = (f & 15) * 4;
      int r = kt0 + rr;
      float4 kv = make_float4(0.f,0.f,0.f,0.f), vv = make_float4(0.f,0.f,0.f,0.f);
      if (r < KSEL) {
        kv = *(const float4*)&kb[base + (size_t)r*DH_ + dd];
        vv = *(const float4*)&vb[base + (size_t)r*DH_ + dd];
      }
      *(float4*)&KPs[rr][dd] = kv;
      *(float4*)&Vs[rr][dd] = vv;
    }
    __syncthreads();
    float s[4][4] = {};
    for (int d4 = 0; d4 < 64; d4 += 4) {
      float qa[4][4], ka[4][4];
      #pragma unroll
      for (int i = 0; i < 4; ++i) f4tov(*(const float4*)&Qs[tr*4+i][d4], qa[i]);
      #pragma unroll
      for (int j = 0; j < 4; ++j) f4tov(*(const float4*)&KPs[tc*4+j][d4], ka[j]);
      #pragma unroll
      for (int i = 0; i < 4; ++i)
        #pragma unroll
        for (int j = 0; j < 4; ++j)
          s[i][j] += qa[i][0]*ka[j][0] + qa[i][1]*ka[j][1]
                   + qa[i][2]*ka[j][2] + qa[i][3]*ka[j][3];
    }
    #pragma unroll
    for (int i = 0; i < 4; ++i)
      #pragma unroll
      for (int j = 0; j < 4; ++j) {
        float v = s[i][j] * 0.125f;                 // DH^-0.5
        if (kt0 + tc*4 + j >= KSEL) v = -1e30f;
        s[i][j] = v;
      }
    #pragma unroll
    for (int i = 0; i < 4; ++i) {
      float tm = fmaxf(fmaxf(s[i][0], s[i][1]), fmaxf(s[i][2], s[i][3]));
      #pragma unroll
      for (int off = 1; off < 16; off <<= 1) tm = fmaxf(tm, __shfl_xor(tm, off, 64));
      float mnew = fmaxf(m_run[i], tm);
      float corr = __expf(m_run[i] - mnew);
      float rs = 0.f;
      #pragma unroll
      for (int j = 0; j < 4; ++j) { float p = __expf(s[i][j] - mnew); s[i][j] = p; rs += p; }
      #pragma unroll
      for (int off = 1; off < 16; off <<= 1) rs += __shfl_xor(rs, off, 64);
      l_run[i] = l_run[i]*corr + rs;
      m_run[i] = mnew;
      #pragma unroll
      for (int j = 0; j < 4; ++j) acc[i][j] *= corr;
    }
    __syncthreads();                 // everyone done reading K tile
    #pragma unroll
    for (int i = 0; i < 4; ++i)
      *(float4*)&KPs[tr*4+i][tc*4] = make_float4(s[i][0], s[i][1], s[i][2], s[i][3]);
    __syncthreads();
    for (int j4 = 0; j4 < 64; j4 += 4) {
      float pa[4][4], va[4][4];
      #pragma unroll
      for (int i = 0; i < 4; ++i) f4tov(*(const float4*)&KPs[tr*4+i][j4], pa[i]);
      #pragma unroll
      for (int j = 0; j < 4; ++j) f4tov(*(const float4*)&Vs[j4+j][tc*4], va[j]);
      #pragma unroll
      for (int i = 0; i < 4; ++i)
        #pragma unroll
        for (int j = 0; j < 4; ++j)
          acc[i][j] += pa[i][0]*va[0][j] + pa[i][1]*va[1][j]
                     + pa[i][2]*va[2][j] + pa[i][3]*va[3][j];
    }
  }
  #pragma unroll
  for (int i = 0; i < 4; ++i) {
    int r = r0 + tr*4 + i;
    if (r < KSEL) {
      float inv = 1.f / l_run[i];
      float4 o = make_float4(acc[i][0]*inv, acc[i][1]*inv, acc[i][2]*inv, acc[i][3]*inv);
      *(float4*)&sa[((size_t)b*KSEL + r)*C_ + h*DH_ + tc*4] = o;
    }
  }
}

// ---------------- column sums of exp(e) over tokens (bf16 e) ----------------
__global__ __launch_bounds__(256) void k_colsum_part(const unsigned short* __restrict__ e,
                                                     float* __restrict__ psum)
{
  int ncb = blockIdx.x, ic = blockIdx.y, b = blockIdx.z;
  int tid = threadIdx.x, il = tid & 63, nsub = tid >> 6;
  int i = ic*64 + il;
  float s = 0.f;
  for (int n = ncb*512 + nsub; n < ncb*512 + 512; n += 4)
    s += __expf(bf2f(e[((size_t)b*N_ + n)*C_ + i]));
  __shared__ float red[256];
  red[tid] = s; __syncthreads();
  if (nsub == 0)
    psum[((size_t)b*C_ + i)*8 + ncb] = red[il] + red[il+64] + red[il+128] + red[il+192];
}

__global__ __launch_bounds__(256) void k_colsum_comb(const float* __restrict__ psum,
                                                     float* __restrict__ colsum)
{
  int g = blockIdx.x*256 + threadIdx.x;   // 0..4095 = (b, i)
  float s = 0.f;
  #pragma unroll
  for (int c = 0; c < 8; ++c) s += psum[(size_t)g*8 + c];
  colsum[g] = s;
}

// ---------------- softmax value + head-normalize -> a (bf16) ----------------
__global__ __launch_bounds__(256) void k_anorm(const unsigned short* __restrict__ e,
    const float* __restrict__ colsum, unsigned short* __restrict__ ab)
{
  int tid = threadIdx.x, lane = tid & 63, wid = tid >> 6;
  int token = blockIdx.x*4 + wid;
  int b = token >> 12;
  size_t base = (size_t)token*C_ + lane*8;
  uint4 w = *(const uint4*)&e[base];
  float f[8];
  f[0] = __uint_as_float(w.x << 16); f[1] = __uint_as_float(w.x & 0xffff0000u);
  f[2] = __uint_as_float(w.y << 16); f[3] = __uint_as_float(w.y & 0xffff0000u);
  f[4] = __uint_as_float(w.z << 16); f[5] = __uint_as_float(w.z & 0xffff0000u);
  f[6] = __uint_as_float(w.w << 16); f[7] = __uint_as_float(w.w & 0xffff0000u);
  const float* cs = colsum + b*C_ + lane*8;
  float4 c0 = *(const float4*)&cs[0];
  float4 c1 = *(const float4*)&cs[4];
  float a[8];
  a[0] = __expf(f[0])/c0.x; a[1] = __expf(f[1])/c0.y;
  a[2] = __expf(f[2])/c0.z; a[3] = __expf(f[3])/c0.w;
  a[4] = __expf(f[4])/c1.x; a[5] = __expf(f[5])/c1.y;
  a[6] = __expf(f[6])/c1.z; a[7] = __expf(f[7])/c1.w;
  float hs = a[0]+a[1]+a[2]+a[3]+a[4]+a[5]+a[6]+a[7];
  hs += __shfl_xor(hs, 1, 64);
  hs += __shfl_xor(hs, 2, 64);
  hs += __shfl_xor(hs, 4, 64);   // 8-lane group == one head (64 dims)
  hs += 1e-6f;
  float r = 1.f / hs;
  uint4 o;
  o.x = (unsigned)f2bf(a[0]*r) | ((unsigned)f2bf(a[1]*r) << 16);
  o.y = (unsigned)f2bf(a[2]*r) | ((unsigned)f2bf(a[3]*r) << 16);
  o.z = (unsigned)f2bf(a[4]*r) | ((unsigned)f2bf(a[5]*r) << 16);
  o.w = (unsigned)f2bf(a[6]*r) | ((unsigned)f2bf(a[7]*r) << 16);
  *(uint4*)&ab[base] = o;
}

// ---------------- sa@wo + bo, scatter-add alpha*() into d_out ----------------
__global__ __launch_bounds__(256) void k_sa_gemm(const float* __restrict__ sa,
    const float* __restrict__ wo, const float* __restrict__ bo,
    const int* __restrict__ idx, const float* __restrict__ alphap,
    float* __restrict__ out)
{
  __shared__ float As[16][68];
  __shared__ float Bs[16][68];
  int tid = threadIdx.x;
  int mt = blockIdx.x, nt = blockIdx.y, b = blockIdx.z;
  int m0 = mt*64, col0 = nt*64;
  int tr = tid >> 4, tc = tid & 15;
  int m_l = tid >> 2, kq = tid & 3;
  int arow = m0 + m_l; if (arow >= KSEL) arow = 0;
  float acc[4][4] = {};
  for (int k0 = 0; k0 < C_; k0 += 16) {
    float4 av = *(const float4*)&sa[((size_t)b*KSEL + arow)*C_ + k0 + kq*4];
    float4 bv = *(const float4*)&wo[(size_t)(k0 + tr)*C_ + col0 + tc*4];
    As[kq*4+0][m_l] = av.x; As[kq*4+1][m_l] = av.y;
    As[kq*4+2][m_l] = av.z; As[kq*4+3][m_l] = av.w;
    *(float4*)&Bs[tr][tc*4] = bv;
    __syncthreads();
    #pragma unroll
    for (int kk = 0; kk < 16; ++kk) {
      float ar[4], br[4];
      f4tov(*(const float4*)&As[kk][tr*4], ar);
      f4tov(*(const float4*)&Bs[kk][tc*4], br);
      #pragma unroll
      for (int i = 0; i < 4; ++i)
        #pragma unroll
        for (int j = 0; j < 4; ++j) acc[i][j] += ar[i]*br[j];
    }
    __syncthreads();
  }
  float alpha = alphap[0];
  float4 bo4 = *(const float4*)&bo[col0 + tc*4];
  #pragma unroll
  for (int i = 0; i < 4; ++i) {
    int r = m0 + tr*4 + i;
    if (r < KSEL) {
      int token = idx[b*KSEL + r];
      size_t o = ((size_t)b*N_ + token)*C_ + col0 + tc*4;
      float4 cur = *(float4*)&out[o];
      cur.x += alpha*(acc[i][0] + bo4.x);
      cur.y += alpha*(acc[i][1] + bo4.y);
      cur.z += alpha*(acc[i][2] + bo4.z);
      cur.w += alpha*(acc[i][3] + bo4.w);
      *(float4*)&out[o] = cur;
    }
  }
}

extern "C" void kernel_launch(void* const* d_in, const int* in_sizes, int n_in,
                              void* d_out, int out_size, void* d_ws, size_t ws_size,
                              hipStream_t stream)
{
  const float* x     = (const float*)d_in[0];
  const float* temb  = (const float*)d_in[1];
  const float* g_w1  = (const float*)d_in[2];
  const float* g_b1  = (const float*)d_in[3];
  const float* g_w2  = (const float*)d_in[4];
  const float* g_b2  = (const float*)d_in[5];
  const float* wq    = (const float*)d_in[6];
  const float* wk    = (const float*)d_in[7];
  const float* wv    = (const float*)d_in[8];
  const float* wo    = (const float*)d_in[9];
  const float* bo    = (const float*)d_in[10];
  const float* ln_g  = (const float*)d_in[11];
  const float* ln_b  = (const float*)d_in[12];
  const float* ea_k  = (const float*)d_in[13];
  const float* ea_v  = (const float*)d_in[14];
  const float* alpha = (const float*)d_in[15];
  float* out = (float*)d_out;
  float* ws = (float*)d_ws;

  // workspace layout (float offsets); ~95.4 MB
  float* scores  = ws;                          // 4096   (dead after imp_stats)
  float* colsum  = ws;                          // alias: written by colsum_comb
  float* imp     = ws + 4096;                   // 32768  (dead after topk)
  float* psum    = ws + 4096;                   // alias: 32768
  float* mu      = ws + 36864;                  // 32768
  float* rstd    = ws + 69632;                  // 32768
  int*   idx     = (int*)(ws + 102400);         // 4096
  float* qb      = ws + 106496;                 // 1675264
  float* kb      = qb + 1675264;
  float* vb      = kb + 1675264;
  float* sab     = vb + 1675264;                // 1675264
  unsigned short* ebuf  = (unsigned short*)(ws + 6807552);   // 16777216 bf16
  unsigned short* xnb   = (unsigned short*)(ws + 15196160);  // 16777216 bf16 (xn, later a)
  unsigned short* eakb  = (unsigned short*)(ws + 23584768);  // 262144 bf16
  unsigned short* eavb  = (unsigned short*)(ws + 23715840);  // 262144 bf16

  k_gating     <<<dim3(B_),         dim3(256), 0, stream>>>(temb, g_w1, g_b1, g_w2, g_b2, scores);
  k_imp_stats  <<<dim3(B_*N_/4),    dim3(256), 0, stream>>>(x, scores, imp, mu, rstd);
  k_topk       <<<dim3(B_),         dim3(256), 0, stream>>>(imp, idx);
  k_prep       <<<dim3(B_*N_/4),    dim3(256), 0, stream>>>(x, mu, rstd, ln_g, ln_b, xnb);
  k_cvt        <<<dim3(256),        dim3(256), 0, stream>>>(ea_k, eakb);
  k_cvt        <<<dim3(256),        dim3(256), 0, stream>>>(ea_v, eavb);
  k_qkv        <<<dim3(7, 24, B_),  dim3(256), 0, stream>>>(x, idx, wq, wk, wv, qb, kb, vb);
  k_attn       <<<dim3(7, H_, B_),  dim3(256), 0, stream>>>(qb, kb, vb, sab);
  k_mfma_gemm<0><<<dim3(256, 4),    dim3(256), 0, stream>>>(xnb, eakb, ebuf, 0.125f);
  k_colsum_part<<<dim3(8, 8, B_),   dim3(256), 0, stream>>>(ebuf, psum);
  k_colsum_comb<<<dim3(16),         dim3(256), 0, stream>>>(psum, colsum);
  k_anorm      <<<dim3(B_*N_/4),    dim3(256), 0, stream>>>(ebuf, colsum, xnb);
  k_mfma_gemm<1><<<dim3(256, 4),    dim3(256), 0, stream>>>(xnb, eavb, out, 1.0f);
  k_sa_gemm    <<<dim3(7, 8, B_),   dim3(256), 0, stream>>>(sab, wo, bo, idx, alpha, out);
}

// Round 3
// 270.822 us; speedup vs baseline: 2.8982x; 1.4611x over previous
//
#include <hip/hip_runtime.h>
#include <hip/hip_bf16.h>
#include <math.h>

#define B_   8
#define N_   4096
#define C_   512
#define H_   8
#define DH_  64
#define TED_ 1280
#define KSEL 409
#define KPAD 448   // 7*64

typedef __attribute__((ext_vector_type(8))) short bf16x8;
typedef __attribute__((ext_vector_type(4))) float f32x4;

__device__ inline void f4tov(float4 v, float* o) { o[0]=v.x; o[1]=v.y; o[2]=v.z; o[3]=v.w; }

// round-to-nearest-even float -> bf16 bits
__device__ __forceinline__ unsigned short f2bf(float f) {
  unsigned u = __float_as_uint(f);
  unsigned r = u + 0x7fffu + ((u >> 16) & 1u);
  return (unsigned short)(r >> 16);
}
__device__ __forceinline__ float bf2f(unsigned short s) {
  return __uint_as_float(((unsigned)s) << 16);
}

__device__ __forceinline__ void gload16(const void* g, void* l) {
  __builtin_amdgcn_global_load_lds(
      (const __attribute__((address_space(1))) void*)g,
      (__attribute__((address_space(3))) void*)l,
      16, 0, 0);
}

// ---------------- gating: scores[b,c] ----------------
__global__ __launch_bounds__(256) void k_gating(const float* __restrict__ temb,
    const float* __restrict__ g_w1, const float* __restrict__ g_b1,
    const float* __restrict__ g_w2, const float* __restrict__ g_b2,
    float* __restrict__ scores)
{
  __shared__ float red[256];
  __shared__ float hid[64];
  int b = blockIdx.x, tid = threadIdx.x;
  int j = tid & 63, part = tid >> 6;
  const float* te = temb + b*TED_;
  float s = 0.f;
  for (int t = part*320; t < part*320 + 320; ++t)
    s += te[t] * g_w1[t*64 + j];
  red[tid] = s;
  __syncthreads();
  if (part == 0) {
    float v = red[j] + red[j+64] + red[j+128] + red[j+192] + g_b1[j];
    hid[j] = v / (1.f + __expf(-v));   // silu
  }
  __syncthreads();
  for (int c = tid; c < C_; c += 256) {
    float s2 = g_b2[c];
    #pragma unroll 8
    for (int h = 0; h < 64; ++h) s2 += hid[h] * g_w2[h*C_ + c];
    scores[b*C_ + c] = s2;
  }
}

// ---------------- imp + LN stats (one pass over x) ----------------
__global__ __launch_bounds__(256) void k_imp_stats(const float* __restrict__ x,
    const float* __restrict__ scores, float* __restrict__ imp,
    float* __restrict__ mu, float* __restrict__ rstd)
{
  int tid = threadIdx.x, lane = tid & 63, wid = tid >> 6;
  int token = blockIdx.x*4 + wid;
  int b = token >> 12;
  const float4* xr = (const float4*)(x + (size_t)token*C_);
  const float4* sc = (const float4*)(scores + b*C_);
  float si = 0.f, s1 = 0.f, s2 = 0.f;
  #pragma unroll
  for (int jj = 0; jj < 2; ++jj) {
    float4 xv = xr[lane + 64*jj];
    float4 sv = sc[lane + 64*jj];
    si += xv.x*sv.x + xv.y*sv.y + xv.z*sv.z + xv.w*sv.w;
    s1 += xv.x + xv.y + xv.z + xv.w;
    s2 += xv.x*xv.x + xv.y*xv.y + xv.z*xv.z + xv.w*xv.w;
  }
  #pragma unroll
  for (int off = 32; off >= 1; off >>= 1) {
    si += __shfl_xor(si, off, 64);
    s1 += __shfl_xor(s1, off, 64);
    s2 += __shfl_xor(s2, off, 64);
  }
  if (lane == 0) {
    imp[token] = si;
    float m = s1 * (1.f/C_);
    float var = s2 * (1.f/C_) - m*m;
    mu[token] = m;
    rstd[token] = rsqrtf(var + 1e-5f);
  }
}

// ---------------- deterministic radix-select top-k ----------------
__global__ __launch_bounds__(256) void k_topk(const float* __restrict__ imp,
                                              int* __restrict__ idxout)
{
  __shared__ unsigned skey[4096];
  __shared__ int hist[256];
  __shared__ unsigned s_prefix;
  __shared__ int s_kneed;
  __shared__ int sc_sel[256], sc_tie[256];
  int b = blockIdx.x, tid = threadIdx.x;
  for (int i = tid; i < 4096; i += 256) {
    unsigned u = __float_as_uint(imp[b*N_ + i]);
    skey[i] = (u & 0x80000000u) ? ~u : (u | 0x80000000u);  // monotone key
  }
  if (tid == 0) { s_prefix = 0; s_kneed = KSEL; }
  __syncthreads();
  for (int shift = 24; shift >= 0; shift -= 8) {
    hist[tid] = 0;
    __syncthreads();
    unsigned pref = s_prefix;
    for (int i = tid; i < 4096; i += 256) {
      unsigned key = skey[i];
      bool match;
      if (shift == 24) match = true;
      else match = ((key >> (shift + 8)) == pref);
      if (match) atomicAdd(&hist[(key >> shift) & 255], 1);
    }
    __syncthreads();
    if (tid == 0) {
      int need = s_kneed; int d = 255;
      for (; d > 0; --d) { int hh = hist[d]; if (need <= hh) break; need -= hh; }
      s_prefix = (s_prefix << 8) | (unsigned)d;
      s_kneed = need;
    }
    __syncthreads();
  }
  unsigned T = s_prefix;
  int tie_take = s_kneed;
  int lc_sel = 0, lc_tie = 0;
  int i0 = tid * 16;
  for (int e2 = 0; e2 < 16; ++e2) {
    unsigned key = skey[i0 + e2];
    lc_sel += (key > T);
    lc_tie += (key == T);
  }
  sc_sel[tid] = lc_sel; sc_tie[tid] = lc_tie;
  __syncthreads();
  for (int off = 1; off < 256; off <<= 1) {
    int a = 0, c2 = 0;
    if (tid >= off) { a = sc_sel[tid - off]; c2 = sc_tie[tid - off]; }
    __syncthreads();
    sc_sel[tid] += a; sc_tie[tid] += c2;
    __syncthreads();
  }
  int total_gt = sc_sel[255];
  int ps = sc_sel[tid] - lc_sel, pt = sc_tie[tid] - lc_tie;
  for (int e2 = 0; e2 < 16; ++e2) {
    int i = i0 + e2;
    unsigned key = skey[i];
    if (key > T) { idxout[b*KSEL + ps] = i; ++ps; }
    else if (key == T) { if (pt < tie_take) idxout[b*KSEL + total_gt + pt] = i; ++pt; }
  }
}

// ---------------- LN(x) -> bf16 ----------------
__global__ __launch_bounds__(256) void k_prep(const float* __restrict__ x,
    const float* __restrict__ mu, const float* __restrict__ rstd,
    const float* __restrict__ ln_g, const float* __restrict__ ln_b,
    unsigned short* __restrict__ xn)
{
  int tid = threadIdx.x, lane = tid & 63, wid = tid >> 6;
  int token = blockIdx.x*4 + wid;
  size_t base = (size_t)token*C_ + lane*8;
  float m = mu[token], rs = rstd[token];
  float4 v0 = *(const float4*)&x[base];
  float4 v1 = *(const float4*)&x[base + 4];
  float4 g0 = *(const float4*)&ln_g[lane*8];
  float4 g1 = *(const float4*)&ln_g[lane*8 + 4];
  float4 b0 = *(const float4*)&ln_b[lane*8];
  float4 b1 = *(const float4*)&ln_b[lane*8 + 4];
  unsigned r0 = (unsigned)f2bf((v0.x-m)*rs*g0.x + b0.x) | ((unsigned)f2bf((v0.y-m)*rs*g0.y + b0.y) << 16);
  unsigned r1 = (unsigned)f2bf((v0.z-m)*rs*g0.z + b0.z) | ((unsigned)f2bf((v0.w-m)*rs*g0.w + b0.w) << 16);
  unsigned r2 = (unsigned)f2bf((v1.x-m)*rs*g1.x + b1.x) | ((unsigned)f2bf((v1.y-m)*rs*g1.y + b1.y) << 16);
  unsigned r3 = (unsigned)f2bf((v1.z-m)*rs*g1.z + b1.z) | ((unsigned)f2bf((v1.w-m)*rs*g1.w + b1.w) << 16);
  uint4 o; o.x = r0; o.y = r1; o.z = r2; o.w = r3;
  *(uint4*)&xn[base] = o;
}

// ---------------- fp32 -> bf16 convert (row-major keep) ----------------
__global__ __launch_bounds__(256) void k_cvt(const float* __restrict__ src,
                                             unsigned short* __restrict__ dst)
{
  int i = (blockIdx.x*256 + threadIdx.x)*4;
  float4 v = *(const float4*)&src[i];
  unsigned lo = (unsigned)f2bf(v.x) | ((unsigned)f2bf(v.y) << 16);
  unsigned hi = (unsigned)f2bf(v.z) | ((unsigned)f2bf(v.w) << 16);
  uint2 o; o.x = lo; o.y = hi;
  *(uint2*)&dst[i] = o;
}

// ---------------- fp32 [512][512] -> bf16 transposed [out][in] ----------------
__global__ __launch_bounds__(256) void k_cvt_t(const float* __restrict__ W,
                                               unsigned short* __restrict__ Wt)
{
  int idx = blockIdx.x*256 + threadIdx.x;   // 32768 threads
  int o = idx & 511;
  int ig = (idx >> 9) * 8;
  unsigned short r[8];
  #pragma unroll
  for (int j = 0; j < 8; ++j) r[j] = f2bf(W[(size_t)(ig + j)*512 + o]);
  uint4 v;
  v.x = (unsigned)r[0] | ((unsigned)r[1] << 16);
  v.y = (unsigned)r[2] | ((unsigned)r[3] << 16);
  v.z = (unsigned)r[4] | ((unsigned)r[5] << 16);
  v.w = (unsigned)r[6] | ((unsigned)r[7] << 16);
  *(uint4*)&Wt[(size_t)o*512 + ig] = v;
}

// ---------------- gather routed tokens -> bf16, pad to 448 ----------------
__global__ __launch_bounds__(256) void k_gather(const float* __restrict__ x,
    const int* __restrict__ idx, unsigned short* __restrict__ xg)
{
  int tid = threadIdx.x, lane = tid & 63, wid = tid >> 6;
  int gr = blockIdx.x*4 + wid;          // 0..3583
  int b = gr / KPAD, r = gr - b*KPAD;
  uint4 o;
  if (r < KSEL) {
    int tok = idx[b*KSEL + r];
    size_t base = ((size_t)b*N_ + tok)*C_ + lane*8;
    float4 v0 = *(const float4*)&x[base];
    float4 v1 = *(const float4*)&x[base + 4];
    o.x = (unsigned)f2bf(v0.x) | ((unsigned)f2bf(v0.y) << 16);
    o.y = (unsigned)f2bf(v0.z) | ((unsigned)f2bf(v0.w) << 16);
    o.z = (unsigned)f2bf(v1.x) | ((unsigned)f2bf(v1.y) << 16);
    o.w = (unsigned)f2bf(v1.z) | ((unsigned)f2bf(v1.w) << 16);
  } else {
    o.x = o.y = o.z = o.w = 0u;
  }
  *(uint4*)&xg[(size_t)gr*C_ + lane*8] = o;
}

// ---------------- shared 128x128xK=512 MFMA body ----------------
__device__ __forceinline__ void gemm128_body(
    const unsigned short* __restrict__ Arows,
    const unsigned short* __restrict__ Brows,
    unsigned short* As, unsigned short* Bs, f32x4 acc[4][4])
{
  int tid = threadIdx.x;
  int lane = tid & 63, wid = tid >> 6;
  int wr = wid >> 1, wc = wid & 1;
  int srow = tid >> 3, spos = tid & 7;
  int l15 = lane & 15, lh = lane >> 4;
  for (int k0 = 0; k0 < C_; k0 += 64) {
    #pragma unroll
    for (int s = 0; s < 4; ++s) {
      int row = s*32 + srow;
      int chunk = spos ^ (row & 7);
      gload16(&Arows[(size_t)row*C_ + k0 + chunk*8], &As[row*64 + spos*8]);
      gload16(&Brows[(size_t)row*C_ + k0 + chunk*8], &Bs[row*64 + spos*8]);
    }
    __syncthreads();
    #pragma unroll
    for (int kk = 0; kk < 2; ++kk) {
      bf16x8 af[4], bfr[4];
      #pragma unroll
      for (int m = 0; m < 4; ++m) {
        int row = wr*64 + m*16 + l15;
        int chunk = (kk*4 + lh) ^ (row & 7);
        af[m] = *(const bf16x8*)&As[row*64 + chunk*8];
      }
      #pragma unroll
      for (int n = 0; n < 4; ++n) {
        int row = wc*64 + n*16 + l15;
        int chunk = (kk*4 + lh) ^ (row & 7);
        bfr[n] = *(const bf16x8*)&Bs[row*64 + chunk*8];
      }
      #pragma unroll
      for (int m = 0; m < 4; ++m)
        #pragma unroll
        for (int n = 0; n < 4; ++n)
          acc[m][n] = __builtin_amdgcn_mfma_f32_16x16x32_bf16(af[m], bfr[n], acc[m][n], 0, 0, 0);
    }
    __syncthreads();
  }
}

// ---------------- EA GEMMs (EPI 0: scale+bf16 store, EPI 1: f32 store) ----
template<int EPI>
__global__ __launch_bounds__(256) void k_mfma_gemm(
    const unsigned short* __restrict__ A,
    const unsigned short* __restrict__ Bm,
    void* __restrict__ Co, float scale)
{
  __shared__ unsigned short As[128*64];
  __shared__ unsigned short Bs[128*64];
  int tid = threadIdx.x;
  int m0 = blockIdx.x * 128, n0 = blockIdx.y * 128;
  int lane = tid & 63, wid = tid >> 6;
  int wr = wid >> 1, wc = wid & 1;
  int l15 = lane & 15, lh = lane >> 4;
  f32x4 acc[4][4];
  #pragma unroll
  for (int m = 0; m < 4; ++m)
    #pragma unroll
    for (int n = 0; n < 4; ++n) acc[m][n] = (f32x4){0.f,0.f,0.f,0.f};
  gemm128_body(A + (size_t)m0*C_, Bm + (size_t)n0*C_, As, Bs, acc);
  #pragma unroll
  for (int m = 0; m < 4; ++m) {
    int row = m0 + wr*64 + m*16 + lh*4;
    #pragma unroll
    for (int n = 0; n < 4; ++n) {
      int col = n0 + wc*64 + n*16 + l15;
      #pragma unroll
      for (int r = 0; r < 4; ++r) {
        float v = acc[m][n][r] * scale;
        if (EPI == 0) ((unsigned short*)Co)[(size_t)(row + r)*C_ + col] = f2bf(v);
        else          ((float*)Co)[(size_t)(row + r)*C_ + col] = v;
      }
    }
  }
}

// ---------------- QKV MFMA GEMM: z selects weight; V written transposed ----
__global__ __launch_bounds__(256) void k_qkv_gemm(
    const unsigned short* __restrict__ xg,
    const unsigned short* __restrict__ wqt,
    const unsigned short* __restrict__ wkt,
    const unsigned short* __restrict__ wvt,
    unsigned short* __restrict__ qg, unsigned short* __restrict__ kg,
    unsigned short* __restrict__ vt)
{
  __shared__ unsigned short As[128*64];
  __shared__ unsigned short Bs[128*64];
  int tid = threadIdx.x;
  int m0 = blockIdx.x * 128, n0 = blockIdx.y * 128, w = blockIdx.z;
  const unsigned short* Wt = (w == 0) ? wqt : (w == 1) ? wkt : wvt;
  int lane = tid & 63, wid = tid >> 6;
  int wr = wid >> 1, wc = wid & 1;
  int l15 = lane & 15, lh = lane >> 4;
  f32x4 acc[4][4];
  #pragma unroll
  for (int m = 0; m < 4; ++m)
    #pragma unroll
    for (int n = 0; n < 4; ++n) acc[m][n] = (f32x4){0.f,0.f,0.f,0.f};
  gemm128_body(xg + (size_t)m0*C_, Wt + (size_t)n0*C_, As, Bs, acc);
  float scale = (w == 0) ? 0.125f : 1.f;   // fold DH^-0.5 into Q
  #pragma unroll
  for (int m = 0; m < 4; ++m) {
    int rowl = wr*64 + m*16 + lh*4;
    #pragma unroll
    for (int n = 0; n < 4; ++n) {
      int col = n0 + wc*64 + n*16 + l15;
      int h = col >> 6, d = col & 63;
      #pragma unroll
      for (int r = 0; r < 4; ++r) {
        int mr = m0 + rowl + r;
        int b = mr / KPAD, rr = mr - b*KPAD;
        unsigned short v = f2bf(acc[m][n][r] * scale);
        if (w < 2) {
          unsigned short* dst = (w == 0) ? qg : kg;
          dst[(((size_t)(b*H_ + h))*KPAD + rr)*DH_ + d] = v;
        } else {
          vt[(((size_t)(b*H_ + h))*DH_ + d)*KPAD + rr] = v;
        }
      }
    }
  }
}

// ---------------- MFMA flash attention over routed tokens ----------------
__global__ __launch_bounds__(256) void k_attn_mfma(
    const unsigned short* __restrict__ qg, const unsigned short* __restrict__ kg,
    const unsigned short* __restrict__ vt, unsigned short* __restrict__ sab)
{
  __shared__ unsigned short Qs[64*64], Ks[64*64], Vs[64*64], Ps[64*64];
  int tid = threadIdx.x, lane = tid & 63, wid = tid >> 6;
  int qt = blockIdx.x, h = blockIdx.y, b = blockIdx.z;
  int l15 = lane & 15, lh = lane >> 4;
  const unsigned short* qbase = qg + (((size_t)(b*H_ + h))*KPAD + qt*64)*DH_;
  const unsigned short* kbase = kg + ((size_t)(b*H_ + h))*KPAD*DH_;
  const unsigned short* vbase = vt + ((size_t)(b*H_ + h))*DH_*KPAD;
  // stage Q tile (64x64): 512 16B chunks, 2 per thread, lane-contiguous dest
  {
    int c0 = tid, c1 = tid + 256;
    int r0 = c0 >> 3, p0 = c0 & 7;
    int r1 = c1 >> 3, p1 = c1 & 7;
    gload16(&qbase[(size_t)r0*64 + (p0 ^ (r0 & 7))*8], &Qs[c0*8]);
    gload16(&qbase[(size_t)r1*64 + (p1 ^ (r1 & 7))*8], &Qs[c1*8]);
  }
  f32x4 acc_o[4];
  #pragma unroll
  for (int ct = 0; ct < 4; ++ct) acc_o[ct] = (f32x4){0.f,0.f,0.f,0.f};
  float m_run[4], l_run[4];
  #pragma unroll
  for (int r = 0; r < 4; ++r) { m_run[r] = -1e30f; l_run[r] = 0.f; }

  for (int t = 0; t < 7; ++t) {
    int kt0 = t*64;
    // stage K tile + V^T tile
    {
      int c0 = tid, c1 = tid + 256;
      int r0 = c0 >> 3, p0 = c0 & 7;
      int r1 = c1 >> 3, p1 = c1 & 7;
      gload16(&kbase[((size_t)(kt0 + r0))*64 + (p0 ^ (r0 & 7))*8], &Ks[c0*8]);
      gload16(&kbase[((size_t)(kt0 + r1))*64 + (p1 ^ (r1 & 7))*8], &Ks[c1*8]);
      gload16(&vbase[(size_t)r0*KPAD + kt0 + (p0 ^ (r0 & 7))*8], &Vs[c0*8]);
      gload16(&vbase[(size_t)r1*KPAD + kt0 + (p1 ^ (r1 & 7))*8], &Vs[c1*8]);
    }
    __syncthreads();   // drain loads (Q included on t=0)

    // S = Q K^T  (wave stripe: rows wid*16..+15, cols 0..63)
    f32x4 s4[4];
    #pragma unroll
    for (int ct = 0; ct < 4; ++ct) s4[ct] = (f32x4){0.f,0.f,0.f,0.f};
    #pragma unroll
    for (int ks = 0; ks < 2; ++ks) {
      int qrow = wid*16 + l15;
      int qch = (ks*4 + lh) ^ (qrow & 7);
      bf16x8 qa = *(const bf16x8*)&Qs[qrow*64 + qch*8];
      #pragma unroll
      for (int ct = 0; ct < 4; ++ct) {
        int krow = ct*16 + l15;
        int kch = (ks*4 + lh) ^ (krow & 7);
        bf16x8 kb8 = *(const bf16x8*)&Ks[krow*64 + kch*8];
        s4[ct] = __builtin_amdgcn_mfma_f32_16x16x32_bf16(qa, kb8, s4[ct], 0, 0, 0);
      }
    }

    // online softmax (C layout: row = lh*4 + r, col = l15)
    bool valid[4];
    #pragma unroll
    for (int ct = 0; ct < 4; ++ct) valid[ct] = (kt0 + ct*16 + l15) < KSEL;
    #pragma unroll
    for (int r = 0; r < 4; ++r) {
      float sv[4];
      #pragma unroll
      for (int ct = 0; ct < 4; ++ct) sv[ct] = valid[ct] ? s4[ct][r] : -1e30f;
      float tm = fmaxf(fmaxf(sv[0], sv[1]), fmaxf(sv[2], sv[3]));
      #pragma unroll
      for (int off = 1; off < 16; off <<= 1) tm = fmaxf(tm, __shfl_xor(tm, off, 64));
      float mnew = fmaxf(m_run[r], tm);
      float corr = __expf(m_run[r] - mnew);
      float rs = 0.f;
      float p[4];
      #pragma unroll
      for (int ct = 0; ct < 4; ++ct) { p[ct] = __expf(sv[ct] - mnew); rs += p[ct]; }
      #pragma unroll
      for (int off = 1; off < 16; off <<= 1) rs += __shfl_xor(rs, off, 64);
      l_run[r] = l_run[r]*corr + rs;
      m_run[r] = mnew;
      #pragma unroll
      for (int ct = 0; ct < 4; ++ct) acc_o[ct][r] *= corr;
      // write P stripe (per-wave disjoint; in-wave dep handles RAW)
      int rowL = wid*16 + lh*4 + r;
      #pragma unroll
      for (int ct = 0; ct < 4; ++ct) {
        int col = ct*16 + l15;
        Ps[rowL*64 + ((col >> 3) ^ (rowL & 7))*8 + (col & 7)] = f2bf(p[ct]);
      }
    }

    // O += P V   (A = P stripe, B = V^T)
    #pragma unroll
    for (int ks = 0; ks < 2; ++ks) {
      int prow = wid*16 + l15;
      int pch = (ks*4 + lh) ^ (prow & 7);
      bf16x8 pa = *(const bf16x8*)&Ps[prow*64 + pch*8];
      #pragma unroll
      for (int ct = 0; ct < 4; ++ct) {
        int vrow = ct*16 + l15;   // d index
        int vch = (ks*4 + lh) ^ (vrow & 7);
        bf16x8 vb8 = *(const bf16x8*)&Vs[vrow*64 + vch*8];
        acc_o[ct] = __builtin_amdgcn_mfma_f32_16x16x32_bf16(pa, vb8, acc_o[ct], 0, 0, 0);
      }
    }
    __syncthreads();   // all reads done before next staging
  }

  #pragma unroll
  for (int r = 0; r < 4; ++r) {
    int rg = qt*64 + wid*16 + lh*4 + r;
    float inv = 1.f / l_run[r];
    #pragma unroll
    for (int ct = 0; ct < 4; ++ct) {
      int col = h*64 + ct*16 + l15;
      unsigned short v = (rg < KSEL) ? f2bf(acc_o[ct][r] * inv) : (unsigned short)0;
      sab[((size_t)b*KPAD + rg)*C_ + col] = v;
    }
  }
}

// ---------------- out-proj MFMA GEMM, scatter-add alpha*(acc+bo) ----------
__global__ __launch_bounds__(256) void k_saout_gemm(
    const unsigned short* __restrict__ sab,
    const unsigned short* __restrict__ wot,
    const float* __restrict__ bo, const int* __restrict__ idx,
    const float* __restrict__ alphap, float* __restrict__ out)
{
  __shared__ unsigned short As[128*64];
  __shared__ unsigned short Bs[128*64];
  int tid = threadIdx.x;
  int m0 = blockIdx.x * 128, n0 = blockIdx.y * 128;
  int lane = tid & 63, wid = tid >> 6;
  int wr = wid >> 1, wc = wid & 1;
  int l15 = lane & 15, lh = lane >> 4;
  f32x4 acc[4][4];
  #pragma unroll
  for (int m = 0; m < 4; ++m)
    #pragma unroll
    for (int n = 0; n < 4; ++n) acc[m][n] = (f32x4){0.f,0.f,0.f,0.f};
  gemm128_body(sab + (size_t)m0*C_, wot + (size_t)n0*C_, As, Bs, acc);
  float alpha = alphap[0];
  #pragma unroll
  for (int m = 0; m < 4; ++m) {
    int rowl = wr*64 + m*16 + lh*4;
    #pragma unroll
    for (int r = 0; r < 4; ++r) {
      int mr = m0 + rowl + r;
      int b = mr / KPAD, rr = mr - b*KPAD;
      if (rr < KSEL) {
        int token = idx[b*KSEL + rr];
        size_t obase = ((size_t)b*N_ + token)*C_;
        #pragma unroll
        for (int n = 0; n < 4; ++n) {
          int col = n0 + wc*64 + n*16 + l15;
          out[obase + col] += alpha*(acc[m][n][r] + bo[col]);
        }
      }
    }
  }
}

// ---------------- column sums of exp(e) over tokens (bf16 e) ----------------
__global__ __launch_bounds__(256) void k_colsum_part(const unsigned short* __restrict__ e,
                                                     float* __restrict__ psum)
{
  int ncb = blockIdx.x, ic = blockIdx.y, b = blockIdx.z;
  int tid = threadIdx.x, il = tid & 63, nsub = tid >> 6;
  int i = ic*64 + il;
  float s = 0.f;
  for (int n = ncb*512 + nsub; n < ncb*512 + 512; n += 4)
    s += __expf(bf2f(e[((size_t)b*N_ + n)*C_ + i]));
  __shared__ float red[256];
  red[tid] = s; __syncthreads();
  if (nsub == 0)
    psum[((size_t)b*C_ + i)*8 + ncb] = red[il] + red[il+64] + red[il+128] + red[il+192];
}

__global__ __launch_bounds__(256) void k_colsum_comb(const float* __restrict__ psum,
                                                     float* __restrict__ colsum)
{
  int g = blockIdx.x*256 + threadIdx.x;
  float s = 0.f;
  #pragma unroll
  for (int c = 0; c < 8; ++c) s += psum[(size_t)g*8 + c];
  colsum[g] = s;
}

// ---------------- softmax value + head-normalize -> a (bf16) ----------------
__global__ __launch_bounds__(256) void k_anorm(const unsigned short* __restrict__ e,
    const float* __restrict__ colsum, unsigned short* __restrict__ ab)
{
  int tid = threadIdx.x, lane = tid & 63, wid = tid >> 6;
  int token = blockIdx.x*4 + wid;
  int b = token >> 12;
  size_t base = (size_t)token*C_ + lane*8;
  uint4 w = *(const uint4*)&e[base];
  float f[8];
  f[0] = __uint_as_float(w.x << 16); f[1] = __uint_as_float(w.x & 0xffff0000u);
  f[2] = __uint_as_float(w.y << 16); f[3] = __uint_as_float(w.y & 0xffff0000u);
  f[4] = __uint_as_float(w.z << 16); f[5] = __uint_as_float(w.z & 0xffff0000u);
  f[6] = __uint_as_float(w.w << 16); f[7] = __uint_as_float(w.w & 0xffff0000u);
  const float* cs = colsum + b*C_ + lane*8;
  float4 c0 = *(const float4*)&cs[0];
  float4 c1 = *(const float4*)&cs[4];
  float a[8];
  a[0] = __expf(f[0])/c0.x; a[1] = __expf(f[1])/c0.y;
  a[2] = __expf(f[2])/c0.z; a[3] = __expf(f[3])/c0.w;
  a[4] = __expf(f[4])/c1.x; a[5] = __expf(f[5])/c1.y;
  a[6] = __expf(f[6])/c1.z; a[7] = __expf(f[7])/c1.w;
  float hs = a[0]+a[1]+a[2]+a[3]+a[4]+a[5]+a[6]+a[7];
  hs += __shfl_xor(hs, 1, 64);
  hs += __shfl_xor(hs, 2, 64);
  hs += __shfl_xor(hs, 4, 64);
  hs += 1e-6f;
  float r = 1.f / hs;
  uint4 o;
  o.x = (unsigned)f2bf(a[0]*r) | ((unsigned)f2bf(a[1]*r) << 16);
  o.y = (unsigned)f2bf(a[2]*r) | ((unsigned)f2bf(a[3]*r) << 16);
  o.z = (unsigned)f2bf(a[4]*r) | ((unsigned)f2bf(a[5]*r) << 16);
  o.w = (unsigned)f2bf(a[6]*r) | ((unsigned)f2bf(a[7]*r) << 16);
  *(uint4*)&ab[base] = o;
}

extern "C" void kernel_launch(void* const* d_in, const int* in_sizes, int n_in,
                              void* d_out, int out_size, void* d_ws, size_t ws_size,
                              hipStream_t stream)
{
  const float* x     = (const float*)d_in[0];
  const float* temb  = (const float*)d_in[1];
  const float* g_w1  = (const float*)d_in[2];
  const float* g_b1  = (const float*)d_in[3];
  const float* g_w2  = (const float*)d_in[4];
  const float* g_b2  = (const float*)d_in[5];
  const float* wq    = (const float*)d_in[6];
  const float* wk    = (const float*)d_in[7];
  const float* wv    = (const float*)d_in[8];
  const float* wo    = (const float*)d_in[9];
  const float* bo    = (const float*)d_in[10];
  const float* ln_g  = (const float*)d_in[11];
  const float* ln_b  = (const float*)d_in[12];
  const float* ea_k  = (const float*)d_in[13];
  const float* ea_v  = (const float*)d_in[14];
  const float* alpha = (const float*)d_in[15];
  float* out = (float*)d_out;
  float* ws = (float*)d_ws;

  // workspace layout (float offsets); total ~89.0 MB
  float* scores  = ws;                          // 4096 (dead after imp_stats)
  float* colsum  = ws;                          // alias
  float* imp     = ws + 4096;                   // 32768 (dead after topk)
  float* psum    = ws + 4096;                   // alias
  float* mu      = ws + 36864;
  float* rstd    = ws + 69632;
  int*   idx     = (int*)(ws + 102400);         // 4096
  unsigned short* ebuf = (unsigned short*)(ws + 106496);    // 16777216 bf16
  unsigned short* xnb  = (unsigned short*)(ws + 8495104);   // 16777216 bf16 (xn, later a)
  unsigned short* eakb = (unsigned short*)(ws + 16883712);  // 262144 bf16
  unsigned short* eavb = (unsigned short*)(ws + 17014784);  // 262144 bf16
  unsigned short* wqt  = (unsigned short*)(ws + 17145856);  // 262144 bf16
  unsigned short* wkt  = (unsigned short*)(ws + 17276928);
  unsigned short* wvt  = (unsigned short*)(ws + 17408000);
  unsigned short* wot  = (unsigned short*)(ws + 17539072);
  unsigned short* xg   = (unsigned short*)(ws + 17670144);  // [8*448][512] bf16
  unsigned short* qg   = (unsigned short*)(ws + 18587648);  // [8][8][448][64]
  unsigned short* kg   = (unsigned short*)(ws + 19505152);  // [8][8][448][64]
  unsigned short* vtb  = (unsigned short*)(ws + 20422656);  // [8][8][64][448]
  unsigned short* sab  = (unsigned short*)(ws + 21340160);  // [8*448][512]

  k_gating     <<<dim3(B_),          dim3(256), 0, stream>>>(temb, g_w1, g_b1, g_w2, g_b2, scores);
  k_imp_stats  <<<dim3(B_*N_/4),     dim3(256), 0, stream>>>(x, scores, imp, mu, rstd);
  k_topk       <<<dim3(B_),          dim3(256), 0, stream>>>(imp, idx);
  k_prep       <<<dim3(B_*N_/4),     dim3(256), 0, stream>>>(x, mu, rstd, ln_g, ln_b, xnb);
  k_cvt        <<<dim3(256),         dim3(256), 0, stream>>>(ea_k, eakb);
  k_cvt        <<<dim3(256),         dim3(256), 0, stream>>>(ea_v, eavb);
  k_cvt_t      <<<dim3(128),         dim3(256), 0, stream>>>(wq, wqt);
  k_cvt_t      <<<dim3(128),         dim3(256), 0, stream>>>(wk, wkt);
  k_cvt_t      <<<dim3(128),         dim3(256), 0, stream>>>(wv, wvt);
  k_cvt_t      <<<dim3(128),         dim3(256), 0, stream>>>(wo, wot);
  k_gather     <<<dim3(B_*KPAD/4),   dim3(256), 0, stream>>>(x, idx, xg);
  k_qkv_gemm   <<<dim3(28, 4, 3),    dim3(256), 0, stream>>>(xg, wqt, wkt, wvt, qg, kg, vtb);
  k_attn_mfma  <<<dim3(7, H_, B_),   dim3(256), 0, stream>>>(qg, kg, vtb, sab);
  k_mfma_gemm<0><<<dim3(256, 4),     dim3(256), 0, stream>>>(xnb, eakb, ebuf, 0.125f);
  k_colsum_part<<<dim3(8, 8, B_),    dim3(256), 0, stream>>>(ebuf, psum);
  k_colsum_comb<<<dim3(16),          dim3(256), 0, stream>>>(psum, colsum);
  k_anorm      <<<dim3(B_*N_/4),     dim3(256), 0, stream>>>(ebuf, colsum, xnb);
  k_mfma_gemm<1><<<dim3(256, 4),     dim3(256), 0, stream>>>(xnb, eavb, out, 1.0f);
  k_saout_gemm <<<dim3(28, 4),       dim3(256), 0, stream>>>(sab, wot, bo, idx, alpha, out);
}

// Round 4
// 229.829 us; speedup vs baseline: 3.4152x; 1.1784x over previous
//
#include <hip/hip_runtime.h>
#include <hip/hip_bf16.h>
#include <math.h>

#define B_   8
#define N_   4096
#define C_   512
#define H_   8
#define DH_  64
#define TED_ 1280
#define KSEL 409
#define KPAD 448   // 7*64

typedef __attribute__((ext_vector_type(8))) short bf16x8;
typedef __attribute__((ext_vector_type(4))) float f32x4;

// round-to-nearest-even float -> bf16 bits
__device__ __forceinline__ unsigned short f2bf(float f) {
  unsigned u = __float_as_uint(f);
  unsigned r = u + 0x7fffu + ((u >> 16) & 1u);
  return (unsigned short)(r >> 16);
}
__device__ __forceinline__ float bf2f(unsigned short s) {
  return __uint_as_float(((unsigned)s) << 16);
}

__device__ __forceinline__ void gload16(const void* g, void* l) {
  __builtin_amdgcn_global_load_lds(
      (const __attribute__((address_space(1))) void*)g,
      (__attribute__((address_space(3))) void*)l,
      16, 0, 0);
}

// ---------------- gating: scores[b,c] ----------------
__global__ __launch_bounds__(256) void k_gating(const float* __restrict__ temb,
    const float* __restrict__ g_w1, const float* __restrict__ g_b1,
    const float* __restrict__ g_w2, const float* __restrict__ g_b2,
    float* __restrict__ scores)
{
  __shared__ float red[256];
  __shared__ float hid[64];
  int b = blockIdx.x, tid = threadIdx.x;
  int j = tid & 63, part = tid >> 6;
  const float* te = temb + b*TED_;
  float s = 0.f;
  for (int t = part*320; t < part*320 + 320; ++t)
    s += te[t] * g_w1[t*64 + j];
  red[tid] = s;
  __syncthreads();
  if (part == 0) {
    float v = red[j] + red[j+64] + red[j+128] + red[j+192] + g_b1[j];
    hid[j] = v / (1.f + __expf(-v));   // silu
  }
  __syncthreads();
  for (int c = tid; c < C_; c += 256) {
    float s2 = g_b2[c];
    #pragma unroll 8
    for (int h = 0; h < 64; ++h) s2 += hid[h] * g_w2[h*C_ + c];
    scores[b*C_ + c] = s2;
  }
}

// ------- fused: importance dot + LN stats + LN(x)->bf16 (one pass over x) ----
__global__ __launch_bounds__(256) void k_imp_prep(const float* __restrict__ x,
    const float* __restrict__ scores, const float* __restrict__ ln_g,
    const float* __restrict__ ln_b, float* __restrict__ imp,
    unsigned short* __restrict__ xn)
{
  int tid = threadIdx.x, lane = tid & 63, wid = tid >> 6;
  int token = blockIdx.x*4 + wid;
  int b = token >> 12;
  size_t base = (size_t)token*C_ + lane*8;
  float4 v0 = *(const float4*)&x[base];
  float4 v1 = *(const float4*)&x[base + 4];
  const float* sc = scores + b*C_ + lane*8;
  float4 sv0 = *(const float4*)&sc[0];
  float4 sv1 = *(const float4*)&sc[4];
  float si = v0.x*sv0.x + v0.y*sv0.y + v0.z*sv0.z + v0.w*sv0.w
           + v1.x*sv1.x + v1.y*sv1.y + v1.z*sv1.z + v1.w*sv1.w;
  float s1 = v0.x+v0.y+v0.z+v0.w + v1.x+v1.y+v1.z+v1.w;
  float s2 = v0.x*v0.x+v0.y*v0.y+v0.z*v0.z+v0.w*v0.w
           + v1.x*v1.x+v1.y*v1.y+v1.z*v1.z+v1.w*v1.w;
  #pragma unroll
  for (int off = 32; off >= 1; off >>= 1) {
    si += __shfl_xor(si, off, 64);
    s1 += __shfl_xor(s1, off, 64);
    s2 += __shfl_xor(s2, off, 64);
  }
  if (lane == 0) imp[token] = si;
  float m = s1 * (1.f/C_);
  float rs = rsqrtf(s2 * (1.f/C_) - m*m + 1e-5f);
  float4 g0 = *(const float4*)&ln_g[lane*8];
  float4 g1 = *(const float4*)&ln_g[lane*8 + 4];
  float4 b0 = *(const float4*)&ln_b[lane*8];
  float4 b1 = *(const float4*)&ln_b[lane*8 + 4];
  uint4 o;
  o.x = (unsigned)f2bf((v0.x-m)*rs*g0.x + b0.x) | ((unsigned)f2bf((v0.y-m)*rs*g0.y + b0.y) << 16);
  o.y = (unsigned)f2bf((v0.z-m)*rs*g0.z + b0.z) | ((unsigned)f2bf((v0.w-m)*rs*g0.w + b0.w) << 16);
  o.z = (unsigned)f2bf((v1.x-m)*rs*g1.x + b1.x) | ((unsigned)f2bf((v1.y-m)*rs*g1.y + b1.y) << 16);
  o.w = (unsigned)f2bf((v1.z-m)*rs*g1.z + b1.z) | ((unsigned)f2bf((v1.w-m)*rs*g1.w + b1.w) << 16);
  *(uint4*)&xn[base] = o;
}

// -------- deterministic radix-select top-k (parallel bin selection) --------
__global__ __launch_bounds__(256) void k_topk(const float* __restrict__ imp,
                                              int* __restrict__ idxout)
{
  __shared__ unsigned skey[4096];
  __shared__ int hist[256];
  __shared__ unsigned s_prefix;
  __shared__ int s_kneed;
  __shared__ int sc_sel[256], sc_tie[256];
  int b = blockIdx.x, tid = threadIdx.x;
  int lane = tid & 63, wid = tid >> 6;
  for (int i = tid; i < 4096; i += 256) {
    unsigned u = __float_as_uint(imp[b*N_ + i]);
    skey[i] = (u & 0x80000000u) ? ~u : (u | 0x80000000u);  // monotone key
  }
  if (tid == 0) { s_prefix = 0; s_kneed = KSEL; }
  __syncthreads();
  for (int shift = 24; shift >= 0; shift -= 8) {
    hist[tid] = 0;
    __syncthreads();
    unsigned pref = s_prefix;
    int need0 = s_kneed;
    for (int i = tid; i < 4096; i += 256) {
      unsigned key = skey[i];
      bool match = (shift == 24) || ((key >> (shift + 8)) == pref);
      if (match) atomicAdd(&hist[(key >> shift) & 255], 1);
    }
    __syncthreads();
    if (wid == 0) {   // wave 0: parallel suffix-scan selection, no barriers
      int h0 = hist[lane*4+0], h1 = hist[lane*4+1];
      int h2 = hist[lane*4+2], h3 = hist[lane*4+3];
      int lt = h0 + h1 + h2 + h3;
      int sfx = lt;
      #pragma unroll
      for (int off = 1; off < 64; off <<= 1) {
        int v = __shfl_down(sfx, off, 64);
        sfx += (lane + off < 64) ? v : 0;
      }
      // sfx = sum of lane-totals for lanes >= lane
      int e3 = sfx - lt;      // keys in bins above this lane's top bin
      int e2 = e3 + h3;
      int e1 = e2 + h2;
      int e0 = e1 + h1;
      int ej0[4] = {e0, e1, e2, e3};
      int hj0[4] = {h0, h1, h2, h3};
      #pragma unroll
      for (int j = 0; j < 4; ++j) {
        if (ej0[j] < need0 && need0 <= ej0[j] + hj0[j]) {
          s_prefix = (pref << 8) | (unsigned)(lane*4 + j);
          s_kneed = need0 - ej0[j];
        }
      }
    }
    __syncthreads();
  }
  unsigned T = s_prefix;      // key of the KSEL-th largest
  int tie_take = s_kneed;     // how many ==T to take (lowest indices)
  int lc_sel = 0, lc_tie = 0;
  int i0 = tid * 16;
  for (int e2 = 0; e2 < 16; ++e2) {
    unsigned key = skey[i0 + e2];
    lc_sel += (key > T);
    lc_tie += (key == T);
  }
  sc_sel[tid] = lc_sel; sc_tie[tid] = lc_tie;
  __syncthreads();
  for (int off = 1; off < 256; off <<= 1) {   // inclusive scan
    int a = 0, c2 = 0;
    if (tid >= off) { a = sc_sel[tid - off]; c2 = sc_tie[tid - off]; }
    __syncthreads();
    sc_sel[tid] += a; sc_tie[tid] += c2;
    __syncthreads();
  }
  int total_gt = sc_sel[255];
  int ps = sc_sel[tid] - lc_sel, pt = sc_tie[tid] - lc_tie;
  for (int e2 = 0; e2 < 16; ++e2) {
    int i = i0 + e2;
    unsigned key = skey[i];
    if (key > T) { idxout[b*KSEL + ps] = i; ++ps; }
    else if (key == T) { if (pt < tie_take) idxout[b*KSEL + total_gt + pt] = i; ++pt; }
  }
}

// ------- fp32 -> bf16 convert, 2 row-major arrays (blockIdx.y selects) -----
__global__ __launch_bounds__(256) void k_cvt2(const float* __restrict__ sa,
    const float* __restrict__ sb, unsigned short* __restrict__ da,
    unsigned short* __restrict__ db)
{
  const float* src = blockIdx.y ? sb : sa;
  unsigned short* dst = blockIdx.y ? db : da;
  int i = (blockIdx.x*256 + threadIdx.x)*4;
  float4 v = *(const float4*)&src[i];
  unsigned lo = (unsigned)f2bf(v.x) | ((unsigned)f2bf(v.y) << 16);
  unsigned hi = (unsigned)f2bf(v.z) | ((unsigned)f2bf(v.w) << 16);
  uint2 o; o.x = lo; o.y = hi;
  *(uint2*)&dst[i] = o;
}

// ------- fp32 [512][512] -> bf16 transposed, 4 arrays (blockIdx.y) ---------
__global__ __launch_bounds__(256) void k_cvt_t4(
    const float* __restrict__ w0, const float* __restrict__ w1,
    const float* __restrict__ w2, const float* __restrict__ w3,
    unsigned short* __restrict__ t0, unsigned short* __restrict__ t1,
    unsigned short* __restrict__ t2, unsigned short* __restrict__ t3)
{
  int wsel = blockIdx.y;
  const float* W = (wsel == 0) ? w0 : (wsel == 1) ? w1 : (wsel == 2) ? w2 : w3;
  unsigned short* Wt = (wsel == 0) ? t0 : (wsel == 1) ? t1 : (wsel == 2) ? t2 : t3;
  int idx = blockIdx.x*256 + threadIdx.x;   // 32768 threads
  int o = idx & 511;
  int ig = (idx >> 9) * 8;
  unsigned short r[8];
  #pragma unroll
  for (int j = 0; j < 8; ++j) r[j] = f2bf(W[(size_t)(ig + j)*512 + o]);
  uint4 v;
  v.x = (unsigned)r[0] | ((unsigned)r[1] << 16);
  v.y = (unsigned)r[2] | ((unsigned)r[3] << 16);
  v.z = (unsigned)r[4] | ((unsigned)r[5] << 16);
  v.w = (unsigned)r[6] | ((unsigned)r[7] << 16);
  *(uint4*)&Wt[(size_t)o*512 + ig] = v;
}

// ---------------- gather routed tokens -> bf16, pad to 448 ----------------
__global__ __launch_bounds__(256) void k_gather(const float* __restrict__ x,
    const int* __restrict__ idx, unsigned short* __restrict__ xg)
{
  int tid = threadIdx.x, lane = tid & 63, wid = tid >> 6;
  int gr = blockIdx.x*4 + wid;          // 0..3583
  int b = gr / KPAD, r = gr - b*KPAD;
  uint4 o;
  if (r < KSEL) {
    int tok = idx[b*KSEL + r];
    size_t base = ((size_t)b*N_ + tok)*C_ + lane*8;
    float4 v0 = *(const float4*)&x[base];
    float4 v1 = *(const float4*)&x[base + 4];
    o.x = (unsigned)f2bf(v0.x) | ((unsigned)f2bf(v0.y) << 16);
    o.y = (unsigned)f2bf(v0.z) | ((unsigned)f2bf(v0.w) << 16);
    o.z = (unsigned)f2bf(v1.x) | ((unsigned)f2bf(v1.y) << 16);
    o.w = (unsigned)f2bf(v1.z) | ((unsigned)f2bf(v1.w) << 16);
  } else {
    o.x = o.y = o.z = o.w = 0u;
  }
  *(uint4*)&xg[(size_t)gr*C_ + lane*8] = o;
}

// ---------------- shared 128x128xK=512 MFMA body ----------------
__device__ __forceinline__ void gemm128_body(
    const unsigned short* __restrict__ Arows,
    const unsigned short* __restrict__ Brows,
    unsigned short* As, unsigned short* Bs, f32x4 acc[4][4])
{
  int tid = threadIdx.x;
  int lane = tid & 63, wid = tid >> 6;
  int wr = wid >> 1, wc = wid & 1;
  int srow = tid >> 3, spos = tid & 7;
  int l15 = lane & 15, lh = lane >> 4;
  for (int k0 = 0; k0 < C_; k0 += 64) {
    #pragma unroll
    for (int s = 0; s < 4; ++s) {
      int row = s*32 + srow;
      int chunk = spos ^ (row & 7);
      gload16(&Arows[(size_t)row*C_ + k0 + chunk*8], &As[row*64 + spos*8]);
      gload16(&Brows[(size_t)row*C_ + k0 + chunk*8], &Bs[row*64 + spos*8]);
    }
    __syncthreads();
    #pragma unroll
    for (int kk = 0; kk < 2; ++kk) {
      bf16x8 af[4], bfr[4];
      #pragma unroll
      for (int m = 0; m < 4; ++m) {
        int row = wr*64 + m*16 + l15;
        int chunk = (kk*4 + lh) ^ (row & 7);
        af[m] = *(const bf16x8*)&As[row*64 + chunk*8];
      }
      #pragma unroll
      for (int n = 0; n < 4; ++n) {
        int row = wc*64 + n*16 + l15;
        int chunk = (kk*4 + lh) ^ (row & 7);
        bfr[n] = *(const bf16x8*)&Bs[row*64 + chunk*8];
      }
      #pragma unroll
      for (int m = 0; m < 4; ++m)
        #pragma unroll
        for (int n = 0; n < 4; ++n)
          acc[m][n] = __builtin_amdgcn_mfma_f32_16x16x32_bf16(af[m], bfr[n], acc[m][n], 0, 0, 0);
    }
    __syncthreads();
  }
}

// ---------------- EA GEMMs (EPI 0: scale+bf16 store, EPI 1: f32 store) ----
template<int EPI>
__global__ __launch_bounds__(256) void k_mfma_gemm(
    const unsigned short* __restrict__ A,
    const unsigned short* __restrict__ Bm,
    void* __restrict__ Co, float scale)
{
  __shared__ unsigned short As[128*64];
  __shared__ unsigned short Bs[128*64];
  int tid = threadIdx.x;
  int m0 = blockIdx.x * 128, n0 = blockIdx.y * 128;
  int lane = tid & 63, wid = tid >> 6;
  int wr = wid >> 1, wc = wid & 1;
  int l15 = lane & 15, lh = lane >> 4;
  f32x4 acc[4][4];
  #pragma unroll
  for (int m = 0; m < 4; ++m)
    #pragma unroll
    for (int n = 0; n < 4; ++n) acc[m][n] = (f32x4){0.f,0.f,0.f,0.f};
  gemm128_body(A + (size_t)m0*C_, Bm + (size_t)n0*C_, As, Bs, acc);
  #pragma unroll
  for (int m = 0; m < 4; ++m) {
    int row = m0 + wr*64 + m*16 + lh*4;
    #pragma unroll
    for (int n = 0; n < 4; ++n) {
      int col = n0 + wc*64 + n*16 + l15;
      #pragma unroll
      for (int r = 0; r < 4; ++r) {
        float v = acc[m][n][r] * scale;
        if (EPI == 0) ((unsigned short*)Co)[(size_t)(row + r)*C_ + col] = f2bf(v);
        else          ((float*)Co)[(size_t)(row + r)*C_ + col] = v;
      }
    }
  }
}

// ---------------- QKV MFMA GEMM: z selects weight; V written transposed ----
__global__ __launch_bounds__(256) void k_qkv_gemm(
    const unsigned short* __restrict__ xg,
    const unsigned short* __restrict__ wqt,
    const unsigned short* __restrict__ wkt,
    const unsigned short* __restrict__ wvt,
    unsigned short* __restrict__ qg, unsigned short* __restrict__ kg,
    unsigned short* __restrict__ vt)
{
  __shared__ unsigned short As[128*64];
  __shared__ unsigned short Bs[128*64];
  int tid = threadIdx.x;
  int m0 = blockIdx.x * 128, n0 = blockIdx.y * 128, w = blockIdx.z;
  const unsigned short* Wt = (w == 0) ? wqt : (w == 1) ? wkt : wvt;
  int lane = tid & 63, wid = tid >> 6;
  int wr = wid >> 1, wc = wid & 1;
  int l15 = lane & 15, lh = lane >> 4;
  f32x4 acc[4][4];
  #pragma unroll
  for (int m = 0; m < 4; ++m)
    #pragma unroll
    for (int n = 0; n < 4; ++n) acc[m][n] = (f32x4){0.f,0.f,0.f,0.f};
  gemm128_body(xg + (size_t)m0*C_, Wt + (size_t)n0*C_, As, Bs, acc);
  float scale = (w == 0) ? 0.125f : 1.f;   // fold DH^-0.5 into Q
  #pragma unroll
  for (int m = 0; m < 4; ++m) {
    int rowl = wr*64 + m*16 + lh*4;
    #pragma unroll
    for (int n = 0; n < 4; ++n) {
      int col = n0 + wc*64 + n*16 + l15;
      int h = col >> 6, d = col & 63;
      #pragma unroll
      for (int r = 0; r < 4; ++r) {
        int mr = m0 + rowl + r;
        int b = mr / KPAD, rr = mr - b*KPAD;
        unsigned short v = f2bf(acc[m][n][r] * scale);
        if (w < 2) {
          unsigned short* dst = (w == 0) ? qg : kg;
          dst[(((size_t)(b*H_ + h))*KPAD + rr)*DH_ + d] = v;
        } else {
          vt[(((size_t)(b*H_ + h))*DH_ + d)*KPAD + rr] = v;
        }
      }
    }
  }
}

// ---------------- MFMA flash attention over routed tokens ----------------
__global__ __launch_bounds__(256) void k_attn_mfma(
    const unsigned short* __restrict__ qg, const unsigned short* __restrict__ kg,
    const unsigned short* __restrict__ vt, unsigned short* __restrict__ sab)
{
  __shared__ unsigned short Qs[64*64], Ks[64*64], Vs[64*64], Ps[64*64];
  int tid = threadIdx.x, lane = tid & 63, wid = tid >> 6;
  int qt = blockIdx.x, h = blockIdx.y, b = blockIdx.z;
  int l15 = lane & 15, lh = lane >> 4;
  const unsigned short* qbase = qg + (((size_t)(b*H_ + h))*KPAD + qt*64)*DH_;
  const unsigned short* kbase = kg + ((size_t)(b*H_ + h))*KPAD*DH_;
  const unsigned short* vbase = vt + ((size_t)(b*H_ + h))*DH_*KPAD;
  {
    int c0 = tid, c1 = tid + 256;
    int r0 = c0 >> 3, p0 = c0 & 7;
    int r1 = c1 >> 3, p1 = c1 & 7;
    gload16(&qbase[(size_t)r0*64 + (p0 ^ (r0 & 7))*8], &Qs[c0*8]);
    gload16(&qbase[(size_t)r1*64 + (p1 ^ (r1 & 7))*8], &Qs[c1*8]);
  }
  f32x4 acc_o[4];
  #pragma unroll
  for (int ct = 0; ct < 4; ++ct) acc_o[ct] = (f32x4){0.f,0.f,0.f,0.f};
  float m_run[4], l_run[4];
  #pragma unroll
  for (int r = 0; r < 4; ++r) { m_run[r] = -1e30f; l_run[r] = 0.f; }

  for (int t = 0; t < 7; ++t) {
    int kt0 = t*64;
    {
      int c0 = tid, c1 = tid + 256;
      int r0 = c0 >> 3, p0 = c0 & 7;
      int r1 = c1 >> 3, p1 = c1 & 7;
      gload16(&kbase[((size_t)(kt0 + r0))*64 + (p0 ^ (r0 & 7))*8], &Ks[c0*8]);
      gload16(&kbase[((size_t)(kt0 + r1))*64 + (p1 ^ (r1 & 7))*8], &Ks[c1*8]);
      gload16(&vbase[(size_t)r0*KPAD + kt0 + (p0 ^ (r0 & 7))*8], &Vs[c0*8]);
      gload16(&vbase[(size_t)r1*KPAD + kt0 + (p1 ^ (r1 & 7))*8], &Vs[c1*8]);
    }
    __syncthreads();

    f32x4 s4[4];
    #pragma unroll
    for (int ct = 0; ct < 4; ++ct) s4[ct] = (f32x4){0.f,0.f,0.f,0.f};
    #pragma unroll
    for (int ks = 0; ks < 2; ++ks) {
      int qrow = wid*16 + l15;
      int qch = (ks*4 + lh) ^ (qrow & 7);
      bf16x8 qa = *(const bf16x8*)&Qs[qrow*64 + qch*8];
      #pragma unroll
      for (int ct = 0; ct < 4; ++ct) {
        int krow = ct*16 + l15;
        int kch = (ks*4 + lh) ^ (krow & 7);
        bf16x8 kb8 = *(const bf16x8*)&Ks[krow*64 + kch*8];
        s4[ct] = __builtin_amdgcn_mfma_f32_16x16x32_bf16(qa, kb8, s4[ct], 0, 0, 0);
      }
    }

    bool valid[4];
    #pragma unroll
    for (int ct = 0; ct < 4; ++ct) valid[ct] = (kt0 + ct*16 + l15) < KSEL;
    #pragma unroll
    for (int r = 0; r < 4; ++r) {
      float sv[4];
      #pragma unroll
      for (int ct = 0; ct < 4; ++ct) sv[ct] = valid[ct] ? s4[ct][r] : -1e30f;
      float tm = fmaxf(fmaxf(sv[0], sv[1]), fmaxf(sv[2], sv[3]));
      #pragma unroll
      for (int off = 1; off < 16; off <<= 1) tm = fmaxf(tm, __shfl_xor(tm, off, 64));
      float mnew = fmaxf(m_run[r], tm);
      float corr = __expf(m_run[r] - mnew);
      float rs = 0.f;
      float p[4];
      #pragma unroll
      for (int ct = 0; ct < 4; ++ct) { p[ct] = __expf(sv[ct] - mnew); rs += p[ct]; }
      #pragma unroll
      for (int off = 1; off < 16; off <<= 1) rs += __shfl_xor(rs, off, 64);
      l_run[r] = l_run[r]*corr + rs;
      m_run[r] = mnew;
      #pragma unroll
      for (int ct = 0; ct < 4; ++ct) acc_o[ct][r] *= corr;
      int rowL = wid*16 + lh*4 + r;
      #pragma unroll
      for (int ct = 0; ct < 4; ++ct) {
        int col = ct*16 + l15;
        Ps[rowL*64 + ((col >> 3) ^ (rowL & 7))*8 + (col & 7)] = f2bf(p[ct]);
      }
    }

    #pragma unroll
    for (int ks = 0; ks < 2; ++ks) {
      int prow = wid*16 + l15;
      int pch = (ks*4 + lh) ^ (prow & 7);
      bf16x8 pa = *(const bf16x8*)&Ps[prow*64 + pch*8];
      #pragma unroll
      for (int ct = 0; ct < 4; ++ct) {
        int vrow = ct*16 + l15;
        int vch = (ks*4 + lh) ^ (vrow & 7);
        bf16x8 vb8 = *(const bf16x8*)&Vs[vrow*64 + vch*8];
        acc_o[ct] = __builtin_amdgcn_mfma_f32_16x16x32_bf16(pa, vb8, acc_o[ct], 0, 0, 0);
      }
    }
    __syncthreads();
  }

  #pragma unroll
  for (int r = 0; r < 4; ++r) {
    int rg = qt*64 + wid*16 + lh*4 + r;
    float inv = 1.f / l_run[r];
    #pragma unroll
    for (int ct = 0; ct < 4; ++ct) {
      int col = h*64 + ct*16 + l15;
      unsigned short v = (rg < KSEL) ? f2bf(acc_o[ct][r] * inv) : (unsigned short)0;
      sab[((size_t)b*KPAD + rg)*C_ + col] = v;
    }
  }
}

// ---------------- out-proj MFMA GEMM, scatter-add alpha*(acc+bo) ----------
__global__ __launch_bounds__(256) void k_saout_gemm(
    const unsigned short* __restrict__ sab,
    const unsigned short* __restrict__ wot,
    const float* __restrict__ bo, const int* __restrict__ idx,
    const float* __restrict__ alphap, float* __restrict__ out)
{
  __shared__ unsigned short As[128*64];
  __shared__ unsigned short Bs[128*64];
  int tid = threadIdx.x;
  int m0 = blockIdx.x * 128, n0 = blockIdx.y * 128;
  int lane = tid & 63, wid = tid >> 6;
  int wr = wid >> 1, wc = wid & 1;
  int l15 = lane & 15, lh = lane >> 4;
  f32x4 acc[4][4];
  #pragma unroll
  for (int m = 0; m < 4; ++m)
    #pragma unroll
    for (int n = 0; n < 4; ++n) acc[m][n] = (f32x4){0.f,0.f,0.f,0.f};
  gemm128_body(sab + (size_t)m0*C_, wot + (size_t)n0*C_, As, Bs, acc);
  float alpha = alphap[0];
  #pragma unroll
  for (int m = 0; m < 4; ++m) {
    int rowl = wr*64 + m*16 + lh*4;
    #pragma unroll
    for (int r = 0; r < 4; ++r) {
      int mr = m0 + rowl + r;
      int b = mr / KPAD, rr = mr - b*KPAD;
      if (rr < KSEL) {
        int token = idx[b*KSEL + rr];
        size_t obase = ((size_t)b*N_ + token)*C_;
        #pragma unroll
        for (int n = 0; n < 4; ++n) {
          int col = n0 + wc*64 + n*16 + l15;
          out[obase + col] += alpha*(acc[m][n][r] + bo[col]);
        }
      }
    }
  }
}

// ---------------- column sums of exp(e) over tokens (bf16 e) ----------------
__global__ __launch_bounds__(256) void k_colsum_part(const unsigned short* __restrict__ e,
                                                     float* __restrict__ psum)
{
  int ncb = blockIdx.x, ic = blockIdx.y, b = blockIdx.z;
  int tid = threadIdx.x, il = tid & 63, nsub = tid >> 6;
  int i = ic*64 + il;
  float s = 0.f;
  for (int n = ncb*512 + nsub; n < ncb*512 + 512; n += 4)
    s += __expf(bf2f(e[((size_t)b*N_ + n)*C_ + i]));
  __shared__ float red[256];
  red[tid] = s; __syncthreads();
  if (nsub == 0)
    psum[((size_t)b*C_ + i)*8 + ncb] = red[il] + red[il+64] + red[il+128] + red[il+192];
}

__global__ __launch_bounds__(256) void k_colsum_comb(const float* __restrict__ psum,
                                                     float* __restrict__ colsum)
{
  int g = blockIdx.x*256 + threadIdx.x;
  float s = 0.f;
  #pragma unroll
  for (int c = 0; c < 8; ++c) s += psum[(size_t)g*8 + c];
  colsum[g] = s;
}

// ---------------- softmax value + head-normalize -> a (bf16) ----------------
__global__ __launch_bounds__(256) void k_anorm(const unsigned short* __restrict__ e,
    const float* __restrict__ colsum, unsigned short* __restrict__ ab)
{
  int tid = threadIdx.x, lane = tid & 63, wid = tid >> 6;
  int token = blockIdx.x*4 + wid;
  int b = token >> 12;
  size_t base = (size_t)token*C_ + lane*8;
  uint4 w = *(const uint4*)&e[base];
  float f[8];
  f[0] = __uint_as_float(w.x << 16); f[1] = __uint_as_float(w.x & 0xffff0000u);
  f[2] = __uint_as_float(w.y << 16); f[3] = __uint_as_float(w.y & 0xffff0000u);
  f[4] = __uint_as_float(w.z << 16); f[5] = __uint_as_float(w.z & 0xffff0000u);
  f[6] = __uint_as_float(w.w << 16); f[7] = __uint_as_float(w.w & 0xffff0000u);
  const float* cs = colsum + b*C_ + lane*8;
  float4 c0 = *(const float4*)&cs[0];
  float4 c1 = *(const float4*)&cs[4];
  float a[8];
  a[0] = __expf(f[0])/c0.x; a[1] = __expf(f[1])/c0.y;
  a[2] = __expf(f[2])/c0.z; a[3] = __expf(f[3])/c0.w;
  a[4] = __expf(f[4])/c1.x; a[5] = __expf(f[5])/c1.y;
  a[6] = __expf(f[6])/c1.z; a[7] = __expf(f[7])/c1.w;
  float hs = a[0]+a[1]+a[2]+a[3]+a[4]+a[5]+a[6]+a[7];
  hs += __shfl_xor(hs, 1, 64);
  hs += __shfl_xor(hs, 2, 64);
  hs += __shfl_xor(hs, 4, 64);
  hs += 1e-6f;
  float r = 1.f / hs;
  uint4 o;
  o.x = (unsigned)f2bf(a[0]*r) | ((unsigned)f2bf(a[1]*r) << 16);
  o.y = (unsigned)f2bf(a[2]*r) | ((unsigned)f2bf(a[3]*r) << 16);
  o.z = (unsigned)f2bf(a[4]*r) | ((unsigned)f2bf(a[5]*r) << 16);
  o.w = (unsigned)f2bf(a[6]*r) | ((unsigned)f2bf(a[7]*r) << 16);
  *(uint4*)&ab[base] = o;
}

extern "C" void kernel_launch(void* const* d_in, const int* in_sizes, int n_in,
                              void* d_out, int out_size, void* d_ws, size_t ws_size,
                              hipStream_t stream)
{
  const float* x     = (const float*)d_in[0];
  const float* temb  = (const float*)d_in[1];
  const float* g_w1  = (const float*)d_in[2];
  const float* g_b1  = (const float*)d_in[3];
  const float* g_w2  = (const float*)d_in[4];
  const float* g_b2  = (const float*)d_in[5];
  const float* wq    = (const float*)d_in[6];
  const float* wk    = (const float*)d_in[7];
  const float* wv    = (const float*)d_in[8];
  const float* wo    = (const float*)d_in[9];
  const float* bo    = (const float*)d_in[10];
  const float* ln_g  = (const float*)d_in[11];
  const float* ln_b  = (const float*)d_in[12];
  const float* ea_k  = (const float*)d_in[13];
  const float* ea_v  = (const float*)d_in[14];
  const float* alpha = (const float*)d_in[15];
  float* out = (float*)d_out;
  float* ws = (float*)d_ws;

  // workspace layout (float offsets)
  float* scores  = ws;                          // 4096 (dead after imp_prep)
  float* colsum  = ws;                          // alias
  float* imp     = ws + 4096;                   // 32768 (dead after topk)
  float* psum    = ws + 4096;                   // alias
  int*   idx     = (int*)(ws + 102400);         // 4096
  unsigned short* ebuf = (unsigned short*)(ws + 106496);    // 16777216 bf16
  unsigned short* xnb  = (unsigned short*)(ws + 8495104);   // 16777216 bf16 (xn, later a)
  unsigned short* eakb = (unsigned short*)(ws + 16883712);  // 262144 bf16
  unsigned short* eavb = (unsigned short*)(ws + 17014784);
  unsigned short* wqt  = (unsigned short*)(ws + 17145856);
  unsigned short* wkt  = (unsigned short*)(ws + 17276928);
  unsigned short* wvt  = (unsigned short*)(ws + 17408000);
  unsigned short* wot  = (unsigned short*)(ws + 17539072);
  unsigned short* xg   = (unsigned short*)(ws + 17670144);  // [8*448][512] bf16
  unsigned short* qg   = (unsigned short*)(ws + 18587648);  // [8][8][448][64]
  unsigned short* kg   = (unsigned short*)(ws + 19505152);
  unsigned short* vtb  = (unsigned short*)(ws + 20422656);  // [8][8][64][448]
  unsigned short* sab  = (unsigned short*)(ws + 21340160);  // [8*448][512]

  k_gating     <<<dim3(B_),          dim3(256), 0, stream>>>(temb, g_w1, g_b1, g_w2, g_b2, scores);
  k_imp_prep   <<<dim3(B_*N_/4),     dim3(256), 0, stream>>>(x, scores, ln_g, ln_b, imp, xnb);
  k_topk       <<<dim3(B_),          dim3(256), 0, stream>>>(imp, idx);
  k_cvt2       <<<dim3(256, 2),      dim3(256), 0, stream>>>(ea_k, ea_v, eakb, eavb);
  k_cvt_t4     <<<dim3(128, 4),      dim3(256), 0, stream>>>(wq, wk, wv, wo, wqt, wkt, wvt, wot);
  k_gather     <<<dim3(B_*KPAD/4),   dim3(256), 0, stream>>>(x, idx, xg);
  k_qkv_gemm   <<<dim3(28, 4, 3),    dim3(256), 0, stream>>>(xg, wqt, wkt, wvt, qg, kg, vtb);
  k_attn_mfma  <<<dim3(7, H_, B_),   dim3(256), 0, stream>>>(qg, kg, vtb, sab);
  k_mfma_gemm<0><<<dim3(256, 4),     dim3(256), 0, stream>>>(xnb, eakb, ebuf, 0.125f);
  k_colsum_part<<<dim3(8, 8, B_),    dim3(256), 0, stream>>>(ebuf, psum);
  k_colsum_comb<<<dim3(16),          dim3(256), 0, stream>>>(psum, colsum);
  k_anorm      <<<dim3(B_*N_/4),     dim3(256), 0, stream>>>(ebuf, colsum, xnb);
  k_mfma_gemm<1><<<dim3(256, 4),     dim3(256), 0, stream>>>(xnb, eavb, out, 1.0f);
  k_saout_gemm <<<dim3(28, 4),       dim3(256), 0, stream>>>(sab, wot, bo, idx, alpha, out);
}

// Round 5
// 197.986 us; speedup vs baseline: 3.9645x; 1.1608x over previous
//
#include <hip/hip_runtime.h>
#include <hip/hip_bf16.h>
#include <math.h>

#define B_   8
#define N_   4096
#define C_   512
#define H_   8
#define DH_  64
#define TED_ 1280
#define KSEL 409
#define KPAD 448   // 7*64

typedef __attribute__((ext_vector_type(8))) short bf16x8;
typedef __attribute__((ext_vector_type(4))) float f32x4;

// round-to-nearest-even float -> bf16 bits
__device__ __forceinline__ unsigned short f2bf(float f) {
  unsigned u = __float_as_uint(f);
  unsigned r = u + 0x7fffu + ((u >> 16) & 1u);
  return (unsigned short)(r >> 16);
}
__device__ __forceinline__ float bf2f(unsigned short s) {
  return __uint_as_float(((unsigned)s) << 16);
}

__device__ __forceinline__ void gload16(const void* g, void* l) {
  __builtin_amdgcn_global_load_lds(
      (const __attribute__((address_space(1))) void*)g,
      (__attribute__((address_space(3))) void*)l,
      16, 0, 0);
}

// ---------------- gating: scores[b,c] ----------------
__global__ __launch_bounds__(256) void k_gating(const float* __restrict__ temb,
    const float* __restrict__ g_w1, const float* __restrict__ g_b1,
    const float* __restrict__ g_w2, const float* __restrict__ g_b2,
    float* __restrict__ scores)
{
  __shared__ float red[256];
  __shared__ float hid[64];
  int b = blockIdx.x, tid = threadIdx.x;
  int j = tid & 63, part = tid >> 6;
  const float* te = temb + b*TED_;
  float s = 0.f;
  for (int t = part*320; t < part*320 + 320; ++t)
    s += te[t] * g_w1[t*64 + j];
  red[tid] = s;
  __syncthreads();
  if (part == 0) {
    float v = red[j] + red[j+64] + red[j+128] + red[j+192] + g_b1[j];
    hid[j] = v / (1.f + __expf(-v));   // silu
  }
  __syncthreads();
  for (int c = tid; c < C_; c += 256) {
    float s2 = g_b2[c];
    #pragma unroll 8
    for (int h = 0; h < 64; ++h) s2 += hid[h] * g_w2[h*C_ + c];
    scores[b*C_ + c] = s2;
  }
}

// ------- fused: importance dot + LN stats + LN(x)->bf16 (one pass over x) ----
__global__ __launch_bounds__(256) void k_imp_prep(const float* __restrict__ x,
    const float* __restrict__ scores, const float* __restrict__ ln_g,
    const float* __restrict__ ln_b, float* __restrict__ imp,
    unsigned short* __restrict__ xn)
{
  int tid = threadIdx.x, lane = tid & 63, wid = tid >> 6;
  int token = blockIdx.x*4 + wid;
  int b = token >> 12;
  size_t base = (size_t)token*C_ + lane*8;
  float4 v0 = *(const float4*)&x[base];
  float4 v1 = *(const float4*)&x[base + 4];
  const float* sc = scores + b*C_ + lane*8;
  float4 sv0 = *(const float4*)&sc[0];
  float4 sv1 = *(const float4*)&sc[4];
  float si = v0.x*sv0.x + v0.y*sv0.y + v0.z*sv0.z + v0.w*sv0.w
           + v1.x*sv1.x + v1.y*sv1.y + v1.z*sv1.z + v1.w*sv1.w;
  float s1 = v0.x+v0.y+v0.z+v0.w + v1.x+v1.y+v1.z+v1.w;
  float s2 = v0.x*v0.x+v0.y*v0.y+v0.z*v0.z+v0.w*v0.w
           + v1.x*v1.x+v1.y*v1.y+v1.z*v1.z+v1.w*v1.w;
  #pragma unroll
  for (int off = 32; off >= 1; off >>= 1) {
    si += __shfl_xor(si, off, 64);
    s1 += __shfl_xor(s1, off, 64);
    s2 += __shfl_xor(s2, off, 64);
  }
  if (lane == 0) imp[token] = si;
  float m = s1 * (1.f/C_);
  float rs = rsqrtf(s2 * (1.f/C_) - m*m + 1e-5f);
  float4 g0 = *(const float4*)&ln_g[lane*8];
  float4 g1 = *(const float4*)&ln_g[lane*8 + 4];
  float4 b0 = *(const float4*)&ln_b[lane*8];
  float4 b1 = *(const float4*)&ln_b[lane*8 + 4];
  uint4 o;
  o.x = (unsigned)f2bf((v0.x-m)*rs*g0.x + b0.x) | ((unsigned)f2bf((v0.y-m)*rs*g0.y + b0.y) << 16);
  o.y = (unsigned)f2bf((v0.z-m)*rs*g0.z + b0.z) | ((unsigned)f2bf((v0.w-m)*rs*g0.w + b0.w) << 16);
  o.z = (unsigned)f2bf((v1.x-m)*rs*g1.x + b1.x) | ((unsigned)f2bf((v1.y-m)*rs*g1.y + b1.y) << 16);
  o.w = (unsigned)f2bf((v1.z-m)*rs*g1.z + b1.z) | ((unsigned)f2bf((v1.w-m)*rs*g1.w + b1.w) << 16);
  *(uint4*)&xn[base] = o;
}

// -------- deterministic radix-select top-k (parallel bin selection) --------
__global__ __launch_bounds__(256) void k_topk(const float* __restrict__ imp,
                                              int* __restrict__ idxout)
{
  __shared__ unsigned skey[4096];
  __shared__ int hist[256];
  __shared__ unsigned s_prefix;
  __shared__ int s_kneed;
  __shared__ int sc_sel[256], sc_tie[256];
  int b = blockIdx.x, tid = threadIdx.x;
  int lane = tid & 63, wid = tid >> 6;
  for (int i = tid; i < 4096; i += 256) {
    unsigned u = __float_as_uint(imp[b*N_ + i]);
    skey[i] = (u & 0x80000000u) ? ~u : (u | 0x80000000u);  // monotone key
  }
  if (tid == 0) { s_prefix = 0; s_kneed = KSEL; }
  __syncthreads();
  for (int shift = 24; shift >= 0; shift -= 8) {
    hist[tid] = 0;
    __syncthreads();
    unsigned pref = s_prefix;
    int need0 = s_kneed;
    for (int i = tid; i < 4096; i += 256) {
      unsigned key = skey[i];
      bool match = (shift == 24) || ((key >> (shift + 8)) == pref);
      if (match) atomicAdd(&hist[(key >> shift) & 255], 1);
    }
    __syncthreads();
    if (wid == 0) {   // wave 0: parallel suffix-scan selection
      int h0 = hist[lane*4+0], h1 = hist[lane*4+1];
      int h2 = hist[lane*4+2], h3 = hist[lane*4+3];
      int lt = h0 + h1 + h2 + h3;
      int sfx = lt;
      #pragma unroll
      for (int off = 1; off < 64; off <<= 1) {
        int v = __shfl_down(sfx, off, 64);
        sfx += (lane + off < 64) ? v : 0;
      }
      int e3 = sfx - lt;
      int e2 = e3 + h3;
      int e1 = e2 + h2;
      int e0 = e1 + h1;
      int ej0[4] = {e0, e1, e2, e3};
      int hj0[4] = {h0, h1, h2, h3};
      #pragma unroll
      for (int j = 0; j < 4; ++j) {
        if (ej0[j] < need0 && need0 <= ej0[j] + hj0[j]) {
          s_prefix = (pref << 8) | (unsigned)(lane*4 + j);
          s_kneed = need0 - ej0[j];
        }
      }
    }
    __syncthreads();
  }
  unsigned T = s_prefix;
  int tie_take = s_kneed;
  int lc_sel = 0, lc_tie = 0;
  int i0 = tid * 16;
  for (int e2 = 0; e2 < 16; ++e2) {
    unsigned key = skey[i0 + e2];
    lc_sel += (key > T);
    lc_tie += (key == T);
  }
  sc_sel[tid] = lc_sel; sc_tie[tid] = lc_tie;
  __syncthreads();
  for (int off = 1; off < 256; off <<= 1) {
    int a = 0, c2 = 0;
    if (tid >= off) { a = sc_sel[tid - off]; c2 = sc_tie[tid - off]; }
    __syncthreads();
    sc_sel[tid] += a; sc_tie[tid] += c2;
    __syncthreads();
  }
  int total_gt = sc_sel[255];
  int ps = sc_sel[tid] - lc_sel, pt = sc_tie[tid] - lc_tie;
  for (int e2 = 0; e2 < 16; ++e2) {
    int i = i0 + e2;
    unsigned key = skey[i];
    if (key > T) { idxout[b*KSEL + ps] = i; ++ps; }
    else if (key == T) { if (pt < tie_take) idxout[b*KSEL + total_gt + pt] = i; ++pt; }
  }
}

// ------- fp32 -> bf16 convert, 2 row-major arrays (blockIdx.y selects) -----
__global__ __launch_bounds__(256) void k_cvt2(const float* __restrict__ sa,
    const float* __restrict__ sb, unsigned short* __restrict__ da,
    unsigned short* __restrict__ db)
{
  const float* src = blockIdx.y ? sb : sa;
  unsigned short* dst = blockIdx.y ? db : da;
  int i = (blockIdx.x*256 + threadIdx.x)*4;
  float4 v = *(const float4*)&src[i];
  unsigned lo = (unsigned)f2bf(v.x) | ((unsigned)f2bf(v.y) << 16);
  unsigned hi = (unsigned)f2bf(v.z) | ((unsigned)f2bf(v.w) << 16);
  uint2 o; o.x = lo; o.y = hi;
  *(uint2*)&dst[i] = o;
}

// ------- fp32 [512][512] -> bf16 transposed, 4 arrays (blockIdx.y) ---------
__global__ __launch_bounds__(256) void k_cvt_t4(
    const float* __restrict__ w0, const float* __restrict__ w1,
    const float* __restrict__ w2, const float* __restrict__ w3,
    unsigned short* __restrict__ t0, unsigned short* __restrict__ t1,
    unsigned short* __restrict__ t2, unsigned short* __restrict__ t3)
{
  int wsel = blockIdx.y;
  const float* W = (wsel == 0) ? w0 : (wsel == 1) ? w1 : (wsel == 2) ? w2 : w3;
  unsigned short* Wt = (wsel == 0) ? t0 : (wsel == 1) ? t1 : (wsel == 2) ? t2 : t3;
  int idx = blockIdx.x*256 + threadIdx.x;
  int o = idx & 511;
  int ig = (idx >> 9) * 8;
  unsigned short r[8];
  #pragma unroll
  for (int j = 0; j < 8; ++j) r[j] = f2bf(W[(size_t)(ig + j)*512 + o]);
  uint4 v;
  v.x = (unsigned)r[0] | ((unsigned)r[1] << 16);
  v.y = (unsigned)r[2] | ((unsigned)r[3] << 16);
  v.z = (unsigned)r[4] | ((unsigned)r[5] << 16);
  v.w = (unsigned)r[6] | ((unsigned)r[7] << 16);
  *(uint4*)&Wt[(size_t)o*512 + ig] = v;
}

// ---------------- gather routed tokens -> bf16, pad to 448 ----------------
__global__ __launch_bounds__(256) void k_gather(const float* __restrict__ x,
    const int* __restrict__ idx, unsigned short* __restrict__ xg)
{
  int tid = threadIdx.x, lane = tid & 63, wid = tid >> 6;
  int gr = blockIdx.x*4 + wid;
  int b = gr / KPAD, r = gr - b*KPAD;
  uint4 o;
  if (r < KSEL) {
    int tok = idx[b*KSEL + r];
    size_t base = ((size_t)b*N_ + tok)*C_ + lane*8;
    float4 v0 = *(const float4*)&x[base];
    float4 v1 = *(const float4*)&x[base + 4];
    o.x = (unsigned)f2bf(v0.x) | ((unsigned)f2bf(v0.y) << 16);
    o.y = (unsigned)f2bf(v0.z) | ((unsigned)f2bf(v0.w) << 16);
    o.z = (unsigned)f2bf(v1.x) | ((unsigned)f2bf(v1.y) << 16);
    o.w = (unsigned)f2bf(v1.z) | ((unsigned)f2bf(v1.w) << 16);
  } else {
    o.x = o.y = o.z = o.w = 0u;
  }
  *(uint4*)&xg[(size_t)gr*C_ + lane*8] = o;
}

// ------- 2-phase pipelined 128x128xK=512 MFMA body (double-buffered) -------
__device__ __forceinline__ void stage128(const unsigned short* __restrict__ Arows,
    const unsigned short* __restrict__ Brows, int k0,
    unsigned short* As, unsigned short* Bs, int srow, int spos)
{
  #pragma unroll
  for (int s = 0; s < 4; ++s) {
    int row = s*32 + srow;
    int chunk = spos ^ (row & 7);
    gload16(&Arows[(size_t)row*C_ + k0 + chunk*8], &As[row*64 + spos*8]);
    gload16(&Brows[(size_t)row*C_ + k0 + chunk*8], &Bs[row*64 + spos*8]);
  }
}

__device__ __forceinline__ void gemm128_pipe(
    const unsigned short* __restrict__ Arows,
    const unsigned short* __restrict__ Brows,
    unsigned short* As, unsigned short* Bs,   // each 2*8192 ushorts
    f32x4 acc[4][4])
{
  int tid = threadIdx.x;
  int lane = tid & 63, wid = tid >> 6;
  int wr = wid >> 1, wc = wid & 1;
  int srow = tid >> 3, spos = tid & 7;
  int l15 = lane & 15, lh = lane >> 4;
  stage128(Arows, Brows, 0, As, Bs, srow, spos);
  __syncthreads();
  for (int t = 0; t < 8; ++t) {
    int cur = (t & 1) ? 8192 : 0;
    int nxt = 8192 - cur;
    if (t < 7)
      stage128(Arows, Brows, (t+1)*64, As + nxt, Bs + nxt, srow, spos);
    #pragma unroll
    for (int kk = 0; kk < 2; ++kk) {
      bf16x8 af[4], bfr[4];
      #pragma unroll
      for (int m = 0; m < 4; ++m) {
        int row = wr*64 + m*16 + l15;
        int chunk = (kk*4 + lh) ^ (row & 7);
        af[m] = *(const bf16x8*)&As[cur + row*64 + chunk*8];
      }
      #pragma unroll
      for (int n = 0; n < 4; ++n) {
        int row = wc*64 + n*16 + l15;
        int chunk = (kk*4 + lh) ^ (row & 7);
        bfr[n] = *(const bf16x8*)&Bs[cur + row*64 + chunk*8];
      }
      #pragma unroll
      for (int m = 0; m < 4; ++m)
        #pragma unroll
        for (int n = 0; n < 4; ++n)
          acc[m][n] = __builtin_amdgcn_mfma_f32_16x16x32_bf16(af[m], bfr[n], acc[m][n], 0, 0, 0);
    }
    __syncthreads();   // drains this iter's prefetch (after MFMA phase) + buffer handoff
  }
}

// ------- e = xn @ ea_k^T, scale, bf16 store (vectorized) + fused colsum ----
__global__ __launch_bounds__(256) void k_eak_gemm(
    const unsigned short* __restrict__ A,
    const unsigned short* __restrict__ Bm,
    unsigned short* __restrict__ e, float* __restrict__ colsum)
{
  __shared__ unsigned short As[2*8192];
  __shared__ unsigned short Bs[2*8192];
  __shared__ float csum[128];
  int tid = threadIdx.x;
  int m0 = blockIdx.x * 128, n0 = blockIdx.y * 128;
  int lane = tid & 63, wid = tid >> 6;
  int wr = wid >> 1, wc = wid & 1;
  int l15 = lane & 15, lh = lane >> 4;
  f32x4 acc[4][4];
  #pragma unroll
  for (int m = 0; m < 4; ++m)
    #pragma unroll
    for (int n = 0; n < 4; ++n) acc[m][n] = (f32x4){0.f,0.f,0.f,0.f};
  gemm128_pipe(A + (size_t)m0*C_, Bm + (size_t)n0*C_, As, Bs, acc);
  // epilogue: bf16 tile -> LDS (for vectorized store) + exp column sums
  unsigned short* tile = As;      // 32 KB, free after pipe's final barrier
  if (tid < 128) csum[tid] = 0.f;
  __syncthreads();
  float pc[4] = {0.f, 0.f, 0.f, 0.f};
  #pragma unroll
  for (int m = 0; m < 4; ++m) {
    int row = wr*64 + m*16 + lh*4;
    #pragma unroll
    for (int n = 0; n < 4; ++n) {
      int col = wc*64 + n*16 + l15;
      #pragma unroll
      for (int r = 0; r < 4; ++r) {
        float v = acc[m][n][r] * 0.125f;
        tile[(row + r)*128 + col] = f2bf(v);
        pc[n] += __expf(v);
      }
    }
  }
  #pragma unroll
  for (int n = 0; n < 4; ++n)
    atomicAdd(&csum[wc*64 + n*16 + l15], pc[n]);
  __syncthreads();
  int bb = blockIdx.x >> 5;   // 32 m-tiles per batch
  #pragma unroll
  for (int j = 0; j < 8; ++j) {
    int lin = j*256 + tid;
    int row = lin >> 4, seg = lin & 15;
    *(uint4*)&e[(size_t)(m0 + row)*C_ + n0 + seg*8] = *(const uint4*)&tile[row*128 + seg*8];
  }
  if (tid < 128) atomicAdd(&colsum[bb*C_ + n0 + tid], csum[tid]);
}

// ---------------- ea = a @ ea_v^T -> f32 out ----------------
__global__ __launch_bounds__(256) void k_eav_gemm(
    const unsigned short* __restrict__ A,
    const unsigned short* __restrict__ Bm,
    float* __restrict__ Co)
{
  __shared__ unsigned short As[2*8192];
  __shared__ unsigned short Bs[2*8192];
  int tid = threadIdx.x;
  int m0 = blockIdx.x * 128, n0 = blockIdx.y * 128;
  int lane = tid & 63, wid = tid >> 6;
  int wr = wid >> 1, wc = wid & 1;
  int l15 = lane & 15, lh = lane >> 4;
  f32x4 acc[4][4];
  #pragma unroll
  for (int m = 0; m < 4; ++m)
    #pragma unroll
    for (int n = 0; n < 4; ++n) acc[m][n] = (f32x4){0.f,0.f,0.f,0.f};
  gemm128_pipe(A + (size_t)m0*C_, Bm + (size_t)n0*C_, As, Bs, acc);
  #pragma unroll
  for (int m = 0; m < 4; ++m) {
    int row = m0 + wr*64 + m*16 + lh*4;
    #pragma unroll
    for (int n = 0; n < 4; ++n) {
      int col = n0 + wc*64 + n*16 + l15;
      #pragma unroll
      for (int r = 0; r < 4; ++r)
        Co[(size_t)(row + r)*C_ + col] = acc[m][n][r];
    }
  }
}

// ---------------- QKV MFMA GEMM: z selects weight; V written transposed ----
__global__ __launch_bounds__(256) void k_qkv_gemm(
    const unsigned short* __restrict__ xg,
    const unsigned short* __restrict__ wqt,
    const unsigned short* __restrict__ wkt,
    const unsigned short* __restrict__ wvt,
    unsigned short* __restrict__ qg, unsigned short* __restrict__ kg,
    unsigned short* __restrict__ vt)
{
  __shared__ unsigned short As[2*8192];
  __shared__ unsigned short Bs[2*8192];
  int tid = threadIdx.x;
  int m0 = blockIdx.x * 128, n0 = blockIdx.y * 128, w = blockIdx.z;
  const unsigned short* Wt = (w == 0) ? wqt : (w == 1) ? wkt : wvt;
  int lane = tid & 63, wid = tid >> 6;
  int wr = wid >> 1, wc = wid & 1;
  int l15 = lane & 15, lh = lane >> 4;
  f32x4 acc[4][4];
  #pragma unroll
  for (int m = 0; m < 4; ++m)
    #pragma unroll
    for (int n = 0; n < 4; ++n) acc[m][n] = (f32x4){0.f,0.f,0.f,0.f};
  gemm128_pipe(xg + (size_t)m0*C_, Wt + (size_t)n0*C_, As, Bs, acc);
  float scale = (w == 0) ? 0.125f : 1.f;   // fold DH^-0.5 into Q
  #pragma unroll
  for (int m = 0; m < 4; ++m) {
    int rowl = wr*64 + m*16 + lh*4;
    #pragma unroll
    for (int n = 0; n < 4; ++n) {
      int col = n0 + wc*64 + n*16 + l15;
      int h = col >> 6, d = col & 63;
      #pragma unroll
      for (int r = 0; r < 4; ++r) {
        int mr = m0 + rowl + r;
        int b = mr / KPAD, rr = mr - b*KPAD;
        unsigned short v = f2bf(acc[m][n][r] * scale);
        if (w < 2) {
          unsigned short* dst = (w == 0) ? qg : kg;
          dst[(((size_t)(b*H_ + h))*KPAD + rr)*DH_ + d] = v;
        } else {
          vt[(((size_t)(b*H_ + h))*DH_ + d)*KPAD + rr] = v;
        }
      }
    }
  }
}

// ---------- MFMA flash attention (double-buffered K/V, 1 barrier/tile) -----
__global__ __launch_bounds__(256) void k_attn_mfma(
    const unsigned short* __restrict__ qg, const unsigned short* __restrict__ kg,
    const unsigned short* __restrict__ vt, unsigned short* __restrict__ sab)
{
  __shared__ unsigned short Qs[4096], Ps[4096];
  __shared__ unsigned short Ks[2][4096], Vs[2][4096];
  int tid = threadIdx.x, lane = tid & 63, wid = tid >> 6;
  int qt = blockIdx.x, h = blockIdx.y, b = blockIdx.z;
  int l15 = lane & 15, lh = lane >> 4;
  const unsigned short* qbase = qg + (((size_t)(b*H_ + h))*KPAD + qt*64)*DH_;
  const unsigned short* kbase = kg + ((size_t)(b*H_ + h))*KPAD*DH_;
  const unsigned short* vbase = vt + ((size_t)(b*H_ + h))*DH_*KPAD;
  int c0 = tid, c1 = tid + 256;
  int r0 = c0 >> 3, p0 = c0 & 7;
  int r1 = c1 >> 3, p1 = c1 & 7;
  // prologue: Q + K/V tile 0
  gload16(&qbase[(size_t)r0*64 + (p0 ^ (r0 & 7))*8], &Qs[c0*8]);
  gload16(&qbase[(size_t)r1*64 + (p1 ^ (r1 & 7))*8], &Qs[c1*8]);
  gload16(&kbase[(size_t)r0*64 + (p0 ^ (r0 & 7))*8], &Ks[0][c0*8]);
  gload16(&kbase[(size_t)r1*64 + (p1 ^ (r1 & 7))*8], &Ks[0][c1*8]);
  gload16(&vbase[(size_t)r0*KPAD + (p0 ^ (r0 & 7))*8], &Vs[0][c0*8]);
  gload16(&vbase[(size_t)r1*KPAD + (p1 ^ (r1 & 7))*8], &Vs[0][c1*8]);
  __syncthreads();

  f32x4 acc_o[4];
  #pragma unroll
  for (int ct = 0; ct < 4; ++ct) acc_o[ct] = (f32x4){0.f,0.f,0.f,0.f};
  float m_run[4], l_run[4];
  #pragma unroll
  for (int r = 0; r < 4; ++r) { m_run[r] = -1e30f; l_run[r] = 0.f; }

  for (int t = 0; t < 7; ++t) {
    int cur = t & 1;
    if (t < 6) {
      int kt1 = (t+1)*64;
      int nb = cur ^ 1;
      gload16(&kbase[((size_t)(kt1 + r0))*64 + (p0 ^ (r0 & 7))*8], &Ks[nb][c0*8]);
      gload16(&kbase[((size_t)(kt1 + r1))*64 + (p1 ^ (r1 & 7))*8], &Ks[nb][c1*8]);
      gload16(&vbase[(size_t)r0*KPAD + kt1 + (p0 ^ (r0 & 7))*8], &Vs[nb][c0*8]);
      gload16(&vbase[(size_t)r1*KPAD + kt1 + (p1 ^ (r1 & 7))*8], &Vs[nb][c1*8]);
    }
    int kt0 = t*64;

    f32x4 s4[4];
    #pragma unroll
    for (int ct = 0; ct < 4; ++ct) s4[ct] = (f32x4){0.f,0.f,0.f,0.f};
    #pragma unroll
    for (int ks = 0; ks < 2; ++ks) {
      int qrow = wid*16 + l15;
      int qch = (ks*4 + lh) ^ (qrow & 7);
      bf16x8 qa = *(const bf16x8*)&Qs[qrow*64 + qch*8];
      #pragma unroll
      for (int ct = 0; ct < 4; ++ct) {
        int krow = ct*16 + l15;
        int kch = (ks*4 + lh) ^ (krow & 7);
        bf16x8 kb8 = *(const bf16x8*)&Ks[cur][krow*64 + kch*8];
        s4[ct] = __builtin_amdgcn_mfma_f32_16x16x32_bf16(qa, kb8, s4[ct], 0, 0, 0);
      }
    }

    bool valid[4];
    #pragma unroll
    for (int ct = 0; ct < 4; ++ct) valid[ct] = (kt0 + ct*16 + l15) < KSEL;
    #pragma unroll
    for (int r = 0; r < 4; ++r) {
      float sv[4];
      #pragma unroll
      for (int ct = 0; ct < 4; ++ct) sv[ct] = valid[ct] ? s4[ct][r] : -1e30f;
      float tm = fmaxf(fmaxf(sv[0], sv[1]), fmaxf(sv[2], sv[3]));
      #pragma unroll
      for (int off = 1; off < 16; off <<= 1) tm = fmaxf(tm, __shfl_xor(tm, off, 64));
      float mnew = fmaxf(m_run[r], tm);
      float corr = __expf(m_run[r] - mnew);
      float rs = 0.f;
      float p[4];
      #pragma unroll
      for (int ct = 0; ct < 4; ++ct) { p[ct] = __expf(sv[ct] - mnew); rs += p[ct]; }
      #pragma unroll
      for (int off = 1; off < 16; off <<= 1) rs += __shfl_xor(rs, off, 64);
      l_run[r] = l_run[r]*corr + rs;
      m_run[r] = mnew;
      #pragma unroll
      for (int ct = 0; ct < 4; ++ct) acc_o[ct][r] *= corr;
      int rowL = wid*16 + lh*4 + r;
      #pragma unroll
      for (int ct = 0; ct < 4; ++ct) {
        int col = ct*16 + l15;
        Ps[rowL*64 + ((col >> 3) ^ (rowL & 7))*8 + (col & 7)] = f2bf(p[ct]);
      }
    }

    #pragma unroll
    for (int ks = 0; ks < 2; ++ks) {
      int prow = wid*16 + l15;
      int pch = (ks*4 + lh) ^ (prow & 7);
      bf16x8 pa = *(const bf16x8*)&Ps[prow*64 + pch*8];
      #pragma unroll
      for (int ct = 0; ct < 4; ++ct) {
        int vrow = ct*16 + l15;
        int vch = (ks*4 + lh) ^ (vrow & 7);
        bf16x8 vb8 = *(const bf16x8*)&Vs[cur][vrow*64 + vch*8];
        acc_o[ct] = __builtin_amdgcn_mfma_f32_16x16x32_bf16(pa, vb8, acc_o[ct], 0, 0, 0);
      }
    }
    __syncthreads();   // drains prefetch + protects Ks/Vs[cur^1] handoff
  }

  #pragma unroll
  for (int r = 0; r < 4; ++r) {
    int rg = qt*64 + wid*16 + lh*4 + r;
    float inv = 1.f / l_run[r];
    #pragma unroll
    for (int ct = 0; ct < 4; ++ct) {
      int col = h*64 + ct*16 + l15;
      unsigned short v = (rg < KSEL) ? f2bf(acc_o[ct][r] * inv) : (unsigned short)0;
      sab[((size_t)b*KPAD + rg)*C_ + col] = v;
    }
  }
}

// ---------------- out-proj MFMA GEMM, scatter-add alpha*(acc+bo) ----------
__global__ __launch_bounds__(256) void k_saout_gemm(
    const unsigned short* __restrict__ sab,
    const unsigned short* __restrict__ wot,
    const float* __restrict__ bo, const int* __restrict__ idx,
    const float* __restrict__ alphap, float* __restrict__ out)
{
  __shared__ unsigned short As[2*8192];
  __shared__ unsigned short Bs[2*8192];
  int tid = threadIdx.x;
  int m0 = blockIdx.x * 128, n0 = blockIdx.y * 128;
  int lane = tid & 63, wid = tid >> 6;
  int wr = wid >> 1, wc = wid & 1;
  int l15 = lane & 15, lh = lane >> 4;
  f32x4 acc[4][4];
  #pragma unroll
  for (int m = 0; m < 4; ++m)
    #pragma unroll
    for (int n = 0; n < 4; ++n) acc[m][n] = (f32x4){0.f,0.f,0.f,0.f};
  gemm128_pipe(sab + (size_t)m0*C_, wot + (size_t)n0*C_, As, Bs, acc);
  float alpha = alphap[0];
  #pragma unroll
  for (int m = 0; m < 4; ++m) {
    int rowl = wr*64 + m*16 + lh*4;
    #pragma unroll
    for (int r = 0; r < 4; ++r) {
      int mr = m0 + rowl + r;
      int b = mr / KPAD, rr = mr - b*KPAD;
      if (rr < KSEL) {
        int token = idx[b*KSEL + rr];
        size_t obase = ((size_t)b*N_ + token)*C_;
        #pragma unroll
        for (int n = 0; n < 4; ++n) {
          int col = n0 + wc*64 + n*16 + l15;
          out[obase + col] += alpha*(acc[m][n][r] + bo[col]);
        }
      }
    }
  }
}

// ---------------- softmax value + head-normalize -> a (bf16) ----------------
__global__ __launch_bounds__(256) void k_anorm(const unsigned short* __restrict__ e,
    const float* __restrict__ colsum, unsigned short* __restrict__ ab)
{
  int tid = threadIdx.x, lane = tid & 63, wid = tid >> 6;
  int token = blockIdx.x*4 + wid;
  int b = token >> 12;
  size_t base = (size_t)token*C_ + lane*8;
  uint4 w = *(const uint4*)&e[base];
  float f[8];
  f[0] = __uint_as_float(w.x << 16); f[1] = __uint_as_float(w.x & 0xffff0000u);
  f[2] = __uint_as_float(w.y << 16); f[3] = __uint_as_float(w.y & 0xffff0000u);
  f[4] = __uint_as_float(w.z << 16); f[5] = __uint_as_float(w.z & 0xffff0000u);
  f[6] = __uint_as_float(w.w << 16); f[7] = __uint_as_float(w.w & 0xffff0000u);
  const float* cs = colsum + b*C_ + lane*8;
  float4 c0 = *(const float4*)&cs[0];
  float4 c1 = *(const float4*)&cs[4];
  float a[8];
  a[0] = __expf(f[0])/c0.x; a[1] = __expf(f[1])/c0.y;
  a[2] = __expf(f[2])/c0.z; a[3] = __expf(f[3])/c0.w;
  a[4] = __expf(f[4])/c1.x; a[5] = __expf(f[5])/c1.y;
  a[6] = __expf(f[6])/c1.z; a[7] = __expf(f[7])/c1.w;
  float hs = a[0]+a[1]+a[2]+a[3]+a[4]+a[5]+a[6]+a[7];
  hs += __shfl_xor(hs, 1, 64);
  hs += __shfl_xor(hs, 2, 64);
  hs += __shfl_xor(hs, 4, 64);
  hs += 1e-6f;
  float r = 1.f / hs;
  uint4 o;
  o.x = (unsigned)f2bf(a[0]*r) | ((unsigned)f2bf(a[1]*r) << 16);
  o.y = (unsigned)f2bf(a[2]*r) | ((unsigned)f2bf(a[3]*r) << 16);
  o.z = (unsigned)f2bf(a[4]*r) | ((unsigned)f2bf(a[5]*r) << 16);
  o.w = (unsigned)f2bf(a[6]*r) | ((unsigned)f2bf(a[7]*r) << 16);
  *(uint4*)&ab[base] = o;
}

extern "C" void kernel_launch(void* const* d_in, const int* in_sizes, int n_in,
                              void* d_out, int out_size, void* d_ws, size_t ws_size,
                              hipStream_t stream)
{
  const float* x     = (const float*)d_in[0];
  const float* temb  = (const float*)d_in[1];
  const float* g_w1  = (const float*)d_in[2];
  const float* g_b1  = (const float*)d_in[3];
  const float* g_w2  = (const float*)d_in[4];
  const float* g_b2  = (const float*)d_in[5];
  const float* wq    = (const float*)d_in[6];
  const float* wk    = (const float*)d_in[7];
  const float* wv    = (const float*)d_in[8];
  const float* wo    = (const float*)d_in[9];
  const float* bo    = (const float*)d_in[10];
  const float* ln_g  = (const float*)d_in[11];
  const float* ln_b  = (const float*)d_in[12];
  const float* ea_k  = (const float*)d_in[13];
  const float* ea_v  = (const float*)d_in[14];
  const float* alpha = (const float*)d_in[15];
  float* out = (float*)d_out;
  float* ws = (float*)d_ws;

  // workspace layout (float offsets)
  float* scores  = ws;                          // 4096 (dead after imp_prep)
  float* colsum  = ws;                          // alias (fused colsum target)
  float* imp     = ws + 4096;                   // 32768 (dead after topk)
  int*   idx     = (int*)(ws + 102400);         // 4096
  unsigned short* ebuf = (unsigned short*)(ws + 106496);    // 16777216 bf16
  unsigned short* xnb  = (unsigned short*)(ws + 8495104);   // 16777216 bf16 (xn, later a)
  unsigned short* eakb = (unsigned short*)(ws + 16883712);  // 262144 bf16
  unsigned short* eavb = (unsigned short*)(ws + 17014784);
  unsigned short* wqt  = (unsigned short*)(ws + 17145856);
  unsigned short* wkt  = (unsigned short*)(ws + 17276928);
  unsigned short* wvt  = (unsigned short*)(ws + 17408000);
  unsigned short* wot  = (unsigned short*)(ws + 17539072);
  unsigned short* xg   = (unsigned short*)(ws + 17670144);  // [8*448][512] bf16
  unsigned short* qg   = (unsigned short*)(ws + 18587648);  // [8][8][448][64]
  unsigned short* kg   = (unsigned short*)(ws + 19505152);
  unsigned short* vtb  = (unsigned short*)(ws + 20422656);  // [8][8][64][448]
  unsigned short* sab  = (unsigned short*)(ws + 21340160);  // [8*448][512]

  k_gating     <<<dim3(B_),          dim3(256), 0, stream>>>(temb, g_w1, g_b1, g_w2, g_b2, scores);
  k_imp_prep   <<<dim3(B_*N_/4),     dim3(256), 0, stream>>>(x, scores, ln_g, ln_b, imp, xnb);
  k_topk       <<<dim3(B_),          dim3(256), 0, stream>>>(imp, idx);
  hipMemsetAsync(colsum, 0, 4096*sizeof(float), stream);    // scores dead now
  k_cvt2       <<<dim3(256, 2),      dim3(256), 0, stream>>>(ea_k, ea_v, eakb, eavb);
  k_cvt_t4     <<<dim3(128, 4),      dim3(256), 0, stream>>>(wq, wk, wv, wo, wqt, wkt, wvt, wot);
  k_gather     <<<dim3(B_*KPAD/4),   dim3(256), 0, stream>>>(x, idx, xg);
  k_qkv_gemm   <<<dim3(28, 4, 3),    dim3(256), 0, stream>>>(xg, wqt, wkt, wvt, qg, kg, vtb);
  k_attn_mfma  <<<dim3(7, H_, B_),   dim3(256), 0, stream>>>(qg, kg, vtb, sab);
  k_eak_gemm   <<<dim3(256, 4),      dim3(256), 0, stream>>>(xnb, eakb, ebuf, colsum);
  k_anorm      <<<dim3(B_*N_/4),     dim3(256), 0, stream>>>(ebuf, colsum, xnb);
  k_eav_gemm   <<<dim3(256, 4),      dim3(256), 0, stream>>>(xnb, eavb, out);
  k_saout_gemm <<<dim3(28, 4),       dim3(256), 0, stream>>>(sab, wot, bo, idx, alpha, out);
}